// Round 13
// baseline (649.570 us; speedup 1.0000x reference)
//
#include <hip/hip_runtime.h>
#include <hip/hip_bf16.h>

typedef _Float16 f16;
typedef _Float16 f16x8 __attribute__((ext_vector_type(8)));
typedef _Float16 f16x4 __attribute__((ext_vector_type(4)));
typedef float    f32x4 __attribute__((ext_vector_type(4)));
typedef unsigned long long u64;

constexpr int NB  = 8;
constexpr int NPT = 2048;
constexpr int KK  = 20;
constexpr int PT  = NB * NPT * KK;   // 327680 pixels, layers 1-4
constexpr int BNP = NB * NPT;        // 16384 points (= 2^14)
constexpr float EPS_BN = 1e-5f;
constexpr size_t PLANE = (size_t)BNP * 256;   // one max/min plane (f16 elems)

// ---------- workspace layout (bytes), total ~144.6 MB ----------
constexpr size_t OFF_IDX = 0;                                    // int [KK][BNP] (transposed)
constexpr size_t OFF_WT1 = OFF_IDX + (size_t)BNP * KK * 4;
constexpr size_t OFF_WH2 = OFF_WT1 + 384 * 4;
constexpr size_t OFF_WH3 = OFF_WH2 + 4096 * 2;
constexpr size_t OFF_WH4 = OFF_WH3 + 8192 * 2;
constexpr size_t OFF_WH5 = OFF_WH4 + 32768 * 2;
constexpr size_t OFF_ST  = OFF_WH5 + 262144 * 2;
constexpr size_t OFF_SS  = OFF_ST + 5 * 1024 * 4;
constexpr size_t OFF_CAT = OFF_SS + 5 * 1024 * 4;                // f16 [BNP][512]
constexpr size_t OFF_Y3  = OFF_CAT + (size_t)BNP * 512 * 2;      // f16 [PT][128] (k-major pixels)
constexpr size_t OFF_Y1  = OFF_Y3 + (size_t)PT * 64 * 2;         // aliases upper half of y3
constexpr size_t OFF_Y2  = OFF_Y3 + (size_t)PT * 128 * 2;        // f16 [PT][64]; at L4: 4 planes
constexpr size_t WS_NEED = OFF_Y2 + (size_t)PT * 64 * 2;         // 144,573,952 B

// ---------- diagnostic ----------
__global__ void marker_kernel(float* __restrict__ out, float v) {
    if (threadIdx.x == 0 && blockIdx.x == 0) out[0] = v;
}

// ---------- weight prep ----------
__global__ __launch_bounds__(256) void prep_weights(
        const float* __restrict__ W1, const float* __restrict__ W2,
        const float* __restrict__ W3, const float* __restrict__ W4,
        const float* __restrict__ W5,
        float* __restrict__ wt1, f16* __restrict__ wh2, f16* __restrict__ wh3,
        f16* __restrict__ wh4, f16* __restrict__ wh5) {
    int i = blockIdx.x * 256 + threadIdx.x;
    if (i < 384)    { int o = i / 6, c = i - o * 6; wt1[c * 64 + o] = W1[i]; }
    if (i < 4096)   wh2[i] = (f16)W2[i];
    if (i < 8192)   wh3[i] = (f16)W3[i];
    if (i < 32768)  wh4[i] = (f16)W4[i];
    if (i < 262144) wh5[i] = (f16)W5[i];
}

// ---------- kNN v5 (verified): u64-key queues + bisection + f64 refine ----------
__device__ __forceinline__ float distf(const float* __restrict__ xb, int m,
                                       float xn0, float xn1, float xn2, float sqn) {
    float xm0 = xb[m], xm1 = xb[NPT + m], xm2 = xb[2 * NPT + m];
    float dot = xn0 * xm0 + xn1 * xm1 + xn2 * xm2;
    float sqm = xm0 * xm0 + xm1 * xm1 + xm2 * xm2;
    return 2.f * dot - sqn - sqm;
}
__device__ __forceinline__ u64 mkkey(float d, int m) {
    unsigned u = __float_as_uint(d);
    u = (u & 0x80000000u) ? ~u : (u | 0x80000000u);
    return ((u64)u << 32) | (unsigned)(2047 - m);
}
__device__ __forceinline__ int key2m(u64 k) { return 2047 - (int)(k & 0xFFFFFFFFull); }

__device__ __forceinline__ void qins(u64 k, u64& q0, u64& q1, u64& q2, u64& q3, u64& spill) {
    bool c0 = k > q0, c1 = k > q1, c2 = k > q2, c3 = k > q3;
    u64 drop = c3 ? q3 : k;
    spill = spill > drop ? spill : drop;
    q3 = c2 ? q2 : (c3 ? k : q3);
    q2 = c1 ? q1 : (c2 ? k : q2);
    q1 = c0 ? q0 : (c1 ? k : q1);
    q0 = c0 ? k  : q0;
}

__global__ __launch_bounds__(256) void knn_kernel(const float* __restrict__ x,
                                                  int* __restrict__ idxo) {
    const int lane = threadIdx.x & 63;
    const int wid  = threadIdx.x >> 6;
    const int r    = blockIdx.x * 4 + wid;
    const int b    = r >> 11;
    const int n    = r & 2047;
    const float* xb = x + b * (3 * NPT);

    const float xn0 = xb[n], xn1 = xb[NPT + n], xn2 = xb[2 * NPT + n];
    const float sqn = xn0 * xn0 + xn1 * xn1 + xn2 * xn2;

    u64 q0 = 0, q1 = 0, q2 = 0, q3 = 0, spill = 0;
#pragma unroll
    for (int i = 0; i < 32; ++i) {
        int m = i * 64 + lane;
        qins(mkkey(distf(xb, m, xn0, xn1, xn2, sqn), m), q0, q1, q2, q3, spill);
    }

    __shared__ int cand[4][32];
    int C;

    unsigned lo = 0u, hi = 0xFFFFFFFFu;
#pragma unroll 1
    for (int it = 0; it < 32 && lo < hi; ++it) {
        unsigned span = hi - lo;
        unsigned mid  = lo + (span >> 1) + (span & 1);
        u64 M = (u64)mid << 32;
        int cnt = __popcll(__ballot(q0 >= M)) + __popcll(__ballot(q1 >= M))
                + __popcll(__ballot(q2 >= M)) + __popcll(__ballot(q3 >= M));
        if (cnt >= 26) lo = mid; else hi = mid - 1;
    }
    const u64 T64 = (u64)lo << 32;

    u64 b0 = __ballot(q0 >= T64), b1 = __ballot(q1 >= T64);
    u64 b2 = __ballot(q2 >= T64), b3 = __ballot(q3 >= T64);
    int n0 = __popcll(b0), n1 = __popcll(b1), n2 = __popcll(b2), n3 = __popcll(b3);
    C = n0 + n1 + n2 + n3;
    bool conflict = (__ballot(spill >= T64) != 0ull) || (C > 32);

    if (!conflict) {
        u64 ltm = (1ull << lane) - 1ull;
        if (q0 >= T64) cand[wid][__popcll(b0 & ltm)] = key2m(q0);
        if (q1 >= T64) cand[wid][n0 + __popcll(b1 & ltm)] = key2m(q1);
        if (q2 >= T64) cand[wid][n0 + n1 + __popcll(b2 & ltm)] = key2m(q2);
        if (q3 >= T64) cand[wid][n0 + n1 + n2 + __popcll(b3 & ltm)] = key2m(q3);
    } else {
        C = 26;
#pragma unroll 1
        for (int t = 0; t < 26; ++t) {
            u64 v = q0;
#pragma unroll
            for (int s = 1; s < 64; s <<= 1) {
                u64 ov = __shfl_xor(v, s);
                if (ov > v) v = ov;
            }
            if (lane == 0) cand[wid][t] = key2m(v);
            if (q0 == v) {
                q0 = q1; q1 = q2; q2 = q3; q3 = 0;
                if (!(q0 > spill)) {
                    q0 = q1 = q2 = q3 = 0; spill = 0;
                    for (int ii = 0; ii < 32; ++ii) {
                        int mr = ii * 64 + lane;
                        u64 kr = mkkey(distf(xb, mr, xn0, xn1, xn2, sqn), mr);
                        if (kr < v) qins(kr, q0, q1, q2, q3, spill);
                    }
                }
            }
        }
    }
    __syncthreads();

    int mm = (lane < C) ? cand[wid][lane] : 0;
    const double dxn0 = (double)xn0, dxn1 = (double)xn1, dxn2 = (double)xn2;
    const double dsqn = dxn0 * dxn0 + dxn1 * dxn1 + dxn2 * dxn2;
    double xm0 = (double)xb[mm], xm1 = (double)xb[NPT + mm], xm2 = (double)xb[2 * NPT + mm];
    double ddot = dxn0 * xm0 + dxn1 * xm1 + dxn2 * xm2;
    double dsqm = xm0 * xm0 + xm1 * xm1 + xm2 * xm2;
    double dd   = 2.0 * ddot - dsqn - dsqm;

    int rank = 0;
#pragma unroll 1
    for (int s = 0; s < C; ++s) {
        double ds = __shfl(dd, s);
        int    ms = __shfl(mm, s);
        if (ds > dd || (ds == dd && ms < mm)) ++rank;
    }
    if (lane < C && rank < KK) idxo[rank * BNP + r] = mm;   // transposed write
}

// ---------- conv1 (k-major pixels) + fused per-channel stats ----------
__global__ __launch_bounds__(256) void conv1_kernel(const float* __restrict__ x,
                                                    const int* __restrict__ idx,
                                                    const float* __restrict__ Wt,
                                                    f16* __restrict__ y,
                                                    float* __restrict__ st) {
    const int tid = threadIdx.x, lane = tid & 63, wid = tid >> 6;
    int p = blockIdx.x * 256 + tid;
    int r = p & (BNP - 1);
    int n = r & 2047;
    int b = r >> 11;
    int m = idx[p];
    const float* xb = x + b * (3 * NPT);
    float f3 = xb[n], f4 = xb[NPT + n], f5 = xb[2 * NPT + n];
    float f0 = xb[m] - f3, f1 = xb[NPT + m] - f4, f2 = xb[2 * NPT + m] - f5;
    float fv[6] = { f0, f1, f2, f3, f4, f5 };

    float acc[64];
#pragma unroll
    for (int o = 0; o < 64; ++o) acc[o] = 0.f;
#pragma unroll
    for (int c = 0; c < 6; ++c) {
        float hv = fv[c];
#pragma unroll
        for (int o = 0; o < 64; ++o) acc[o] = fmaf(Wt[c * 64 + o], hv, acc[o]);
    }
    f16* yp = y + (size_t)p * 64;
#pragma unroll
    for (int o = 0; o < 64; ++o) yp[o] = (f16)acc[o];

    __shared__ float lsum[4][64], lsq[4][64];
#pragma unroll
    for (int o = 0; o < 64; ++o) {
        float s = acc[o], q = acc[o] * acc[o];
#pragma unroll
        for (int off = 32; off >= 1; off >>= 1) { s += __shfl_xor(s, off); q += __shfl_xor(q, off); }
        if (lane == 0) { lsum[wid][o] = s; lsq[wid][o] = q; }
    }
    __syncthreads();
    if (tid < 64) {
        atomicAdd(st + tid,       lsum[0][tid] + lsum[1][tid] + lsum[2][tid] + lsum[3][tid]);
        atomicAdd(st + 512 + tid, lsq[0][tid] + lsq[1][tid] + lsq[2][tid] + lsq[3][tid]);
    }
}

// ---------- MFMA GEMM, input-BN applied on load, fused output stats (L2, L3) ----------
template<int CIN, int OBW>
__global__ __launch_bounds__(256) void conv_mfma_kernel(const f16* __restrict__ h,
                                                        const f16* __restrict__ W,
                                                        const float* __restrict__ scshIn,
                                                        f16* __restrict__ y,
                                                        float* __restrict__ st) {
    constexpr int COUT = OBW * 64;
    const int tid = threadIdx.x, lane = tid & 63, wid = tid >> 6;
    const int lr = lane & 15, lg = lane >> 4;
    const int p0 = blockIdx.x * (256 / OBW) + (wid / OBW) * 64;
    const int ob = (wid & (OBW - 1)) * 64;

    f16x8 Bn[CIN / 32][4];
#pragma unroll
    for (int kt = 0; kt < CIN / 32; ++kt) {
        const int koff = kt * 32 + lg * 8;
        const float4 s0 = *(const float4*)(scshIn + koff);
        const float4 s1 = *(const float4*)(scshIn + koff + 4);
        const float4 h0 = *(const float4*)(scshIn + 512 + koff);
        const float4 h1 = *(const float4*)(scshIn + 512 + koff + 4);
        const float scr[8] = { s0.x, s0.y, s0.z, s0.w, s1.x, s1.y, s1.z, s1.w };
        const float shr[8] = { h0.x, h0.y, h0.z, h0.w, h1.x, h1.y, h1.z, h1.w };
#pragma unroll
        for (int pt = 0; pt < 4; ++pt) {
            f16x8 raw = *(const f16x8*)(h + (size_t)(p0 + pt * 16 + lr) * CIN + koff);
            f16x8 Bv;
#pragma unroll
            for (int e = 0; e < 8; ++e)
                Bv[e] = (f16)fmaxf(fmaf((float)raw[e], scr[e], shr[e]), 0.f);
            Bn[kt][pt] = Bv;
        }
    }

    f32x4 acc[4][4];
#pragma unroll
    for (int pt = 0; pt < 4; ++pt)
#pragma unroll
        for (int t = 0; t < 4; ++t) acc[pt][t] = (f32x4){0.f, 0.f, 0.f, 0.f};

#pragma unroll
    for (int kt = 0; kt < CIN / 32; ++kt) {
        const int koff = kt * 32 + lg * 8;
        f16x8 A[4];
#pragma unroll
        for (int t = 0; t < 4; ++t)
            A[t] = *(const f16x8*)(W + (size_t)(ob + 16 * t + lr) * CIN + koff);
#pragma unroll
        for (int pt = 0; pt < 4; ++pt)
#pragma unroll
            for (int t = 0; t < 4; ++t)
                acc[pt][t] = __builtin_amdgcn_mfma_f32_16x16x32_f16(A[t], Bn[kt][pt], acc[pt][t], 0, 0, 0);
    }
#pragma unroll
    for (int pt = 0; pt < 4; ++pt) {
        int px = p0 + pt * 16 + lr;
#pragma unroll
        for (int t = 0; t < 4; ++t) {
            f16x4 v;
            v[0] = (f16)acc[pt][t][0]; v[1] = (f16)acc[pt][t][1];
            v[2] = (f16)acc[pt][t][2]; v[3] = (f16)acc[pt][t][3];
            *(f16x4*)(y + (size_t)px * COUT + ob + 16 * t + 4 * lg) = v;
        }
    }
    __shared__ float lsum[4][64], lsq[4][64];
#pragma unroll
    for (int t = 0; t < 4; ++t)
#pragma unroll
        for (int j = 0; j < 4; ++j) {
            float s = acc[0][t][j] + acc[1][t][j] + acc[2][t][j] + acc[3][t][j];
            float q = acc[0][t][j] * acc[0][t][j] + acc[1][t][j] * acc[1][t][j]
                    + acc[2][t][j] * acc[2][t][j] + acc[3][t][j] * acc[3][t][j];
#pragma unroll
            for (int m2 = 1; m2 < 16; m2 <<= 1) { s += __shfl_xor(s, m2); q += __shfl_xor(q, m2); }
            if (lr == 0) { lsum[wid][16 * t + 4 * lg + j] = s; lsq[wid][16 * t + 4 * lg + j] = q; }
        }
    __syncthreads();
    if (tid < COUT) {
        int obIdx = tid >> 6, c = tid & 63;
        float S = 0.f, Q = 0.f;
#pragma unroll
        for (int w = obIdx; w < 4; w += OBW) { S += lsum[w][c]; Q += lsq[w][c]; }
        atomicAdd(st + tid, S);
        atomicAdd(st + 512 + tid, Q);
    }
}

// ---------- catmax_norm128: in-place bn3+ReLU on y3 (-> h4) + cat[128:256) ----------
// h4 values are bit-identical to the Bv the fused conv4 used to compute on load.
__global__ __launch_bounds__(256) void catmax_norm128(f16* __restrict__ y,
                                                      const float* __restrict__ scsh,
                                                      f16* __restrict__ cat) {
    int i  = blockIdx.x * 256 + threadIdx.x;         // BNP*16 threads
    int r  = i >> 4;
    int cc = (i & 15) * 8;
    float sc[8], sh[8];
#pragma unroll
    for (int e = 0; e < 8; ++e) { sc[e] = scsh[cc + e]; sh[e] = scsh[512 + cc + e]; }
    float mx[8];
#pragma unroll
    for (int e = 0; e < 8; ++e) mx[e] = 0.f;         // post-relu values >= 0
#pragma unroll
    for (int k = 0; k < KK; ++k) {
        f16* p = y + ((size_t)k * BNP + r) * 128 + cc;
        f16x8 v = *(const f16x8*)p;
        f16x8 o;
#pragma unroll
        for (int e = 0; e < 8; ++e) {
            float f = fmaxf(fmaf((float)v[e], sc[e], sh[e]), 0.f);
            o[e] = (f16)f;
            mx[e] = fmaxf(mx[e], f);
        }
        *(f16x8*)p = o;
    }
    f16x8 o;
#pragma unroll
    for (int e = 0; e < 8; ++e) o[e] = (f16)mx[e];
    *(f16x8*)(cat + (size_t)r * 512 + 128 + cc) = o;
}

// ---------- conv4 v5: lean GEMM on pre-normalized h4, k-half split, no LDS ----------
// grid (BNP/16, 2); wave = 16 points x 64 out-ch; 5 iterations of 2 neighbor-k.
// planes: [mxA|mnA|mxB|mnB], each [BNP][256] f16 (in dead y2 region).
__global__ __launch_bounds__(256, 3) void conv4_gemm_mfma(const f16* __restrict__ h,
                                                          const f16* __restrict__ W,
                                                          float* __restrict__ st,
                                                          f16* __restrict__ planes) {
    const int lane = threadIdx.x & 63, wid = threadIdx.x >> 6;
    const int lr = lane & 15, lg = lane >> 4;
    const int r0 = blockIdx.x * 16;
    const int kh = blockIdx.y;                       // 0: k 0..9, 1: k 10..19
    const int ob = wid * 64;

    f32x4 rmax[4], rmin[4], rsum[4], rsq[4];
#pragma unroll
    for (int t = 0; t < 4; ++t) {
        rmax[t] = (f32x4){-3.3e38f, -3.3e38f, -3.3e38f, -3.3e38f};
        rmin[t] = (f32x4){ 3.3e38f,  3.3e38f,  3.3e38f,  3.3e38f};
        rsum[t] = (f32x4){0.f, 0.f, 0.f, 0.f};
        rsq[t]  = (f32x4){0.f, 0.f, 0.f, 0.f};
    }

#pragma unroll 1
    for (int i2 = 0; i2 < 5; ++i2) {
        const int k0 = kh * 10 + i2 * 2;
        f32x4 acc[2][4];
#pragma unroll
        for (int u = 0; u < 2; ++u)
#pragma unroll
            for (int t = 0; t < 4; ++t) acc[u][t] = (f32x4){0.f, 0.f, 0.f, 0.f};

#pragma unroll
        for (int kt = 0; kt < 4; ++kt) {
            const int koff = kt * 32 + lg * 8;
            f16x8 A[4];
#pragma unroll
            for (int t = 0; t < 4; ++t)
                A[t] = *(const f16x8*)(W + (size_t)(ob + 16 * t + lr) * 128 + koff);
            f16x8 B0 = *(const f16x8*)(h + ((size_t)k0 * BNP + r0 + lr) * 128 + koff);
            f16x8 B1 = *(const f16x8*)(h + ((size_t)(k0 + 1) * BNP + r0 + lr) * 128 + koff);
#pragma unroll
            for (int t = 0; t < 4; ++t) {
                acc[0][t] = __builtin_amdgcn_mfma_f32_16x16x32_f16(A[t], B0, acc[0][t], 0, 0, 0);
                acc[1][t] = __builtin_amdgcn_mfma_f32_16x16x32_f16(A[t], B1, acc[1][t], 0, 0, 0);
            }
        }
#pragma unroll
        for (int u = 0; u < 2; ++u)
#pragma unroll
            for (int t = 0; t < 4; ++t)
#pragma unroll
                for (int j = 0; j < 4; ++j) {
                    float v = acc[u][t][j];
                    rmax[t][j] = fmaxf(rmax[t][j], v);
                    rmin[t][j] = fminf(rmin[t][j], v);
                    rsum[t][j] += v;
                    rsq[t][j]  += v * v;
                }
    }

    f16* mxp = planes + (size_t)(kh * 2 + 0) * PLANE;
    f16* mnp = planes + (size_t)(kh * 2 + 1) * PLANE;
#pragma unroll
    for (int t = 0; t < 4; ++t) {
        f16x4 vx, vn;
#pragma unroll
        for (int j = 0; j < 4; ++j) { vx[j] = (f16)rmax[t][j]; vn[j] = (f16)rmin[t][j]; }
        size_t base = (size_t)(r0 + lr) * 256 + ob + 16 * t + 4 * lg;
        *(f16x4*)(mxp + base) = vx;
        *(f16x4*)(mnp + base) = vn;
    }
#pragma unroll
    for (int t = 0; t < 4; ++t)
#pragma unroll
        for (int j = 0; j < 4; ++j) {
            float s = rsum[t][j], q = rsq[t][j];
#pragma unroll
            for (int m2 = 1; m2 < 16; m2 <<= 1) { s += __shfl_xor(s, m2); q += __shfl_xor(q, m2); }
            if (lr == 0) {
                atomicAdd(st + ob + 16 * t + 4 * lg + j, s);
                atomicAdd(st + 512 + ob + 16 * t + 4 * lg + j, q);
            }
        }
}

// ---------- conv4 epilogue: merge k-halves + BN+ReLU (monotone commute) -> cat ----------
__global__ __launch_bounds__(256) void cat4_kernel(const f16* __restrict__ planes,
                                                   const float* __restrict__ scsh,
                                                   f16* __restrict__ cat) {
    int i = blockIdx.x * 256 + threadIdx.x;
    int r = i >> 8, ch = i & 255;
    float sc = scsh[ch], sh = scsh[512 + ch];
    float v;
    if (sc > 0.f) v = fmaxf((float)planes[i], (float)planes[i + 2 * PLANE]);          // mxA,mxB
    else          v = fminf((float)planes[i + PLANE], (float)planes[i + 3 * PLANE]);  // mnA,mnB
    cat[(size_t)r * 512 + 256 + ch] = (f16)fmaxf(fmaf(v, sc, sh), 0.f);
}

// ---------- conv5: waves share px, differ in ob ----------
__global__ __launch_bounds__(256) void conv5_mfma(const f16* __restrict__ cat,
                                                  const f16* __restrict__ W,
                                                  float* __restrict__ out,
                                                  float* __restrict__ st) {
    const int tid = threadIdx.x;
    const int lane = tid & 63, wid = tid >> 6;
    const int lr = lane & 15, lg = lane >> 4;
    const int p0 = blockIdx.x * 64;
    const int ob = blockIdx.y * 256 + wid * 64;

    f32x4 acc[4][4];
#pragma unroll
    for (int pt = 0; pt < 4; ++pt)
#pragma unroll
        for (int t = 0; t < 4; ++t) acc[pt][t] = (f32x4){0.f, 0.f, 0.f, 0.f};

#pragma unroll
    for (int kt = 0; kt < 16; ++kt) {
        const int koff = kt * 32 + lg * 8;
        f16x8 A[4];
#pragma unroll
        for (int t = 0; t < 4; ++t)
            A[t] = *(const f16x8*)(W + (size_t)(ob + 16 * t + lr) * 512 + koff);
#pragma unroll
        for (int pt = 0; pt < 4; ++pt) {
            f16x8 B = *(const f16x8*)(cat + (size_t)(p0 + pt * 16 + lr) * 512 + koff);
#pragma unroll
            for (int t = 0; t < 4; ++t)
                acc[pt][t] = __builtin_amdgcn_mfma_f32_16x16x32_f16(A[t], B, acc[pt][t], 0, 0, 0);
        }
    }
#pragma unroll
    for (int pt = 0; pt < 4; ++pt) {
        int px = p0 + pt * 16 + lr;
        int b = px >> 11, n = px & 2047;
#pragma unroll
        for (int t = 0; t < 4; ++t) {
#pragma unroll
            for (int j = 0; j < 4; ++j) {
                int o = ob + 16 * t + 4 * lg + j;
                out[((size_t)(b * 512 + o)) * 2048 + n] = acc[pt][t][j];
            }
        }
    }
    __shared__ float lsum[4][64], lsq[4][64];
#pragma unroll
    for (int t = 0; t < 4; ++t)
#pragma unroll
        for (int j = 0; j < 4; ++j) {
            float s = acc[0][t][j] + acc[1][t][j] + acc[2][t][j] + acc[3][t][j];
            float q = acc[0][t][j] * acc[0][t][j] + acc[1][t][j] * acc[1][t][j]
                    + acc[2][t][j] * acc[2][t][j] + acc[3][t][j] * acc[3][t][j];
#pragma unroll
            for (int m2 = 1; m2 < 16; m2 <<= 1) { s += __shfl_xor(s, m2); q += __shfl_xor(q, m2); }
            if (lr == 0) { lsum[wid][16 * t + 4 * lg + j] = s; lsq[wid][16 * t + 4 * lg + j] = q; }
        }
    __syncthreads();
    if (tid < 256) {
        int w = tid >> 6, c = tid & 63;
        atomicAdd(st + blockIdx.y * 256 + tid, lsum[w][c]);
        atomicAdd(st + 512 + blockIdx.y * 256 + tid, lsq[w][c]);
    }
}

// ---------- BN finalize ----------
__global__ void finalize_kernel(const float* __restrict__ st, const float* __restrict__ g,
                                const float* __restrict__ bb, float* __restrict__ scsh,
                                int C, float invM) {
    int c = threadIdx.x;
    if (c < C) {
        float mean = st[c] * invM;
        float var  = st[512 + c] * invM - mean * mean;
        float istd = rsqrtf(var + EPS_BN);
        float sc   = g[c] * istd;
        scsh[c]       = sc;
        scsh[512 + c] = bb[c] - mean * sc;
    }
}

// ---------- vectorized catmax (k-major): f16x8 coalesced, BN+max over k -> cat ----------
template<int C>
__global__ __launch_bounds__(256) void catmax_vec(const f16* __restrict__ y,
                                                  const float* __restrict__ scsh,
                                                  f16* __restrict__ cat, int coff) {
    constexpr int CB = C / 8;
    int i  = blockIdx.x * 256 + threadIdx.x;
    int r  = i / CB;
    int cc = (i - r * CB) * 8;
    float sc[8], sh[8];
#pragma unroll
    for (int e = 0; e < 8; ++e) { sc[e] = scsh[cc + e]; sh[e] = scsh[512 + cc + e]; }
    float mx[8];
#pragma unroll
    for (int e = 0; e < 8; ++e) mx[e] = -3.3e38f;
#pragma unroll
    for (int k = 0; k < KK; ++k) {
        f16x8 v = *(const f16x8*)(y + ((size_t)k * BNP + r) * C + cc);
#pragma unroll
        for (int e = 0; e < 8; ++e)
            mx[e] = fmaxf(mx[e], fmaf((float)v[e], sc[e], sh[e]));
    }
    f16x8 o;
#pragma unroll
    for (int e = 0; e < 8; ++e) o[e] = (f16)fmaxf(mx[e], 0.f);
    *(f16x8*)(cat + (size_t)r * 512 + coff + cc) = o;
}

// ---------- final normalize + ReLU on conv5 output in place ----------
__global__ __launch_bounds__(256) void norm5_kernel(float* __restrict__ out,
                                                    const float* __restrict__ scsh) {
    int o = blockIdx.y;
    int r = blockIdx.x * 256 + threadIdx.x;
    int b = r >> 11, n = r & 2047;
    float sc = scsh[o], sh = scsh[512 + o];
    size_t i = ((size_t)(b * 512 + o)) * 2048 + n;
    float v = fmaf(out[i], sc, sh);
    out[i] = v > 0.f ? v : 0.f;
}

extern "C" void kernel_launch(void* const* d_in, const int* in_sizes, int n_in,
                              void* d_out, int out_size, void* d_ws, size_t ws_size,
                              hipStream_t stream) {
    float* out = (float*)d_out;
    if (ws_size < WS_NEED) {
        marker_kernel<<<1, 64, 0, stream>>>(out, 1000.0f + (float)(ws_size >> 20));
        return;
    }

    const float* x  = (const float*)d_in[0];
    const float* W1 = (const float*)d_in[1];
    const float* g1 = (const float*)d_in[2];
    const float* b1 = (const float*)d_in[3];
    const float* W2 = (const float*)d_in[4];
    const float* g2 = (const float*)d_in[5];
    const float* b2 = (const float*)d_in[6];
    const float* W3 = (const float*)d_in[7];
    const float* g3 = (const float*)d_in[8];
    const float* b3 = (const float*)d_in[9];
    const float* W4 = (const float*)d_in[10];
    const float* g4 = (const float*)d_in[11];
    const float* b4 = (const float*)d_in[12];
    const float* W5 = (const float*)d_in[13];
    const float* g5 = (const float*)d_in[14];
    const float* b5 = (const float*)d_in[15];

    char*  ws    = (char*)d_ws;
    int*   idx   = (int*)(ws + OFF_IDX);
    float* wt1   = (float*)(ws + OFF_WT1);
    f16*   wh2   = (f16*)(ws + OFF_WH2);
    f16*   wh3   = (f16*)(ws + OFF_WH3);
    f16*   wh4   = (f16*)(ws + OFF_WH4);
    f16*   wh5   = (f16*)(ws + OFF_WH5);
    float* stats = (float*)(ws + OFF_ST);
    float* scsh  = (float*)(ws + OFF_SS);
    f16*   cat   = (f16*)(ws + OFF_CAT);
    f16*   y1    = (f16*)(ws + OFF_Y1);
    f16*   y2    = (f16*)(ws + OFF_Y2);
    f16*   y3    = (f16*)(ws + OFF_Y3);     // becomes h4 after catmax_norm128
    f16*   planes = (f16*)(ws + OFF_Y2);    // 4 x 8MB max/min planes (y2 dead at L4)

    hipMemsetAsync(stats, 0, 5 * 1024 * sizeof(float), stream);

    prep_weights<<<1024, 256, 0, stream>>>(W1, W2, W3, W4, W5, wt1, wh2, wh3, wh4, wh5);
    knn_kernel<<<4096, 256, 0, stream>>>(x, idx);

    const float invM  = 1.0f / (float)PT;
    const float invM5 = 1.0f / (float)BNP;

    // L1: 6 -> 64 (raw y1, stats fused)
    conv1_kernel<<<PT / 256, 256, 0, stream>>>(x, idx, wt1, y1, stats + 0);
    finalize_kernel<<<1, 512, 0, stream>>>(stats + 0, g1, b1, scsh + 0, 64, invM);
    catmax_vec<64><<<BNP * 8 / 256, 256, 0, stream>>>(y1, scsh + 0, cat, 0);

    // L2: 64 -> 64 (BN1 on load; stats fused)
    conv_mfma_kernel<64, 1><<<PT / 256, 256, 0, stream>>>(y1, wh2, scsh + 0, y2, stats + 1024);
    finalize_kernel<<<1, 512, 0, stream>>>(stats + 1024, g2, b2, scsh + 1024, 64, invM);
    catmax_vec<64><<<BNP * 8 / 256, 256, 0, stream>>>(y2, scsh + 1024, cat, 64);

    // L3: 64 -> 128 (BN2 on load; OBW=2; clobbers dead y1; stats fused)
    conv_mfma_kernel<64, 2><<<PT / 128, 256, 0, stream>>>(y2, wh3, scsh + 1024, y3, stats + 2048);
    finalize_kernel<<<1, 512, 0, stream>>>(stats + 2048, g3, b3, scsh + 2048, 128, invM);

    // bn3+ReLU in place (y3 -> h4) + cat[128:256)
    catmax_norm128<<<BNP * 16 / 256, 256, 0, stream>>>(y3, scsh + 2048, cat);

    // L4: lean GEMM on h4, k-half split; stats + raw max/min planes
    conv4_gemm_mfma<<<dim3(BNP / 16, 2), 256, 0, stream>>>(y3, wh4, stats + 3072, planes);
    finalize_kernel<<<1, 512, 0, stream>>>(stats + 3072, g4, b4, scsh + 3072, 256, invM);
    cat4_kernel<<<BNP, 256, 0, stream>>>(planes, scsh + 3072, cat);

    // L5: 512 -> 512 on cat -> d_out raw (stats fused)
    conv5_mfma<<<dim3(BNP / 64, 2), 256, 0, stream>>>(cat, wh5, out, stats + 4096);
    finalize_kernel<<<1, 512, 0, stream>>>(stats + 4096, g5, b5, scsh + 4096, 512, invM5);
    norm5_kernel<<<dim3(BNP / 256, 512), 256, 0, stream>>>(out, scsh + 4096);
}

// Round 14
// 415.045 us; speedup vs baseline: 1.5651x; 1.5651x over previous
//
#include <hip/hip_runtime.h>
#include <hip/hip_bf16.h>

typedef _Float16 f16;
typedef _Float16 f16x8 __attribute__((ext_vector_type(8)));
typedef _Float16 f16x4 __attribute__((ext_vector_type(4)));
typedef float    f32x4 __attribute__((ext_vector_type(4)));
typedef unsigned long long u64;

constexpr int NB  = 8;
constexpr int NPT = 2048;
constexpr int KK  = 20;
constexpr int PT  = NB * NPT * KK;   // 327680 pixels, layers 1-4
constexpr int BNP = NB * NPT;        // 16384 points (= 2^14)
constexpr float EPS_BN = 1e-5f;
constexpr int NREP = 64;             // stats replica banks

// ---------- workspace layout (bytes) ----------
constexpr size_t OFF_IDX = 0;                                    // int [KK][BNP] (transposed)
constexpr size_t OFF_WT1 = OFF_IDX + (size_t)BNP * KK * 4;
constexpr size_t OFF_WH2 = OFF_WT1 + 384 * 4;
constexpr size_t OFF_WH3 = OFF_WH2 + 4096 * 2;
constexpr size_t OFF_WH4 = OFF_WH3 + 8192 * 2;
constexpr size_t OFF_WH5 = OFF_WH4 + 32768 * 2;
constexpr size_t OFF_ST  = OFF_WH5 + 262144 * 2;                 // (kept; unused now)
constexpr size_t OFF_SS  = OFF_ST + 5 * 1024 * 4;
constexpr size_t OFF_CAT = OFF_SS + 5 * 1024 * 4;                // f16 [BNP][512]
constexpr size_t OFF_Y3  = OFF_CAT + (size_t)BNP * 512 * 2;      // f16 [PT][128] (k-major pixels)
constexpr size_t OFF_Y1  = OFF_Y3 + (size_t)PT * 64 * 2;         // aliases upper half of y3
constexpr size_t OFF_Y2  = OFF_Y3 + (size_t)PT * 128 * 2;        // f16 [PT][64]; at L4: mx4|mn4
constexpr size_t OFF_REP = OFF_Y2 + (size_t)PT * 64 * 2;         // f32 [NREP][1024] = 256 KB
constexpr size_t WS_NEED = OFF_REP + (size_t)NREP * 1024 * 4;    // 144,836,096 B (< 145,188,352 known ok)

// ---------- diagnostic ----------
__global__ void marker_kernel(float* __restrict__ out, float v) {
    if (threadIdx.x == 0 && blockIdx.x == 0) out[0] = v;
}

// ---------- async global->LDS (wave-uniform LDS base + lane*16B dest) ----------
__device__ __forceinline__ void gload16(const f16* g, f16* ldsbase) {
    __builtin_amdgcn_global_load_lds(
        (const __attribute__((address_space(1))) void*)g,
        (__attribute__((address_space(3))) void*)ldsbase, 16, 0, 0);
}

// ---------- weight prep ----------
__global__ __launch_bounds__(256) void prep_weights(
        const float* __restrict__ W1, const float* __restrict__ W2,
        const float* __restrict__ W3, const float* __restrict__ W4,
        const float* __restrict__ W5,
        float* __restrict__ wt1, f16* __restrict__ wh2, f16* __restrict__ wh3,
        f16* __restrict__ wh4, f16* __restrict__ wh5) {
    int i = blockIdx.x * 256 + threadIdx.x;
    if (i < 384)    { int o = i / 6, c = i - o * 6; wt1[c * 64 + o] = W1[i]; }
    if (i < 4096)   wh2[i] = (f16)W2[i];
    if (i < 8192)   wh3[i] = (f16)W3[i];
    if (i < 32768)  wh4[i] = (f16)W4[i];
    if (i < 262144) wh5[i] = (f16)W5[i];
}

// ---------- kNN v5 (verified): u64-key queues + bisection + f64 refine ----------
__device__ __forceinline__ float distf(const float* __restrict__ xb, int m,
                                       float xn0, float xn1, float xn2, float sqn) {
    float xm0 = xb[m], xm1 = xb[NPT + m], xm2 = xb[2 * NPT + m];
    float dot = xn0 * xm0 + xn1 * xm1 + xn2 * xm2;
    float sqm = xm0 * xm0 + xm1 * xm1 + xm2 * xm2;
    return 2.f * dot - sqn - sqm;
}
__device__ __forceinline__ u64 mkkey(float d, int m) {
    unsigned u = __float_as_uint(d);
    u = (u & 0x80000000u) ? ~u : (u | 0x80000000u);
    return ((u64)u << 32) | (unsigned)(2047 - m);
}
__device__ __forceinline__ int key2m(u64 k) { return 2047 - (int)(k & 0xFFFFFFFFull); }

__device__ __forceinline__ void qins(u64 k, u64& q0, u64& q1, u64& q2, u64& q3, u64& spill) {
    bool c0 = k > q0, c1 = k > q1, c2 = k > q2, c3 = k > q3;
    u64 drop = c3 ? q3 : k;
    spill = spill > drop ? spill : drop;
    q3 = c2 ? q2 : (c3 ? k : q3);
    q2 = c1 ? q1 : (c2 ? k : q2);
    q1 = c0 ? q0 : (c1 ? k : q1);
    q0 = c0 ? k  : q0;
}

__global__ __launch_bounds__(256) void knn_kernel(const float* __restrict__ x,
                                                  int* __restrict__ idxo) {
    const int lane = threadIdx.x & 63;
    const int wid  = threadIdx.x >> 6;
    const int r    = blockIdx.x * 4 + wid;
    const int b    = r >> 11;
    const int n    = r & 2047;
    const float* xb = x + b * (3 * NPT);

    const float xn0 = xb[n], xn1 = xb[NPT + n], xn2 = xb[2 * NPT + n];
    const float sqn = xn0 * xn0 + xn1 * xn1 + xn2 * xn2;

    u64 q0 = 0, q1 = 0, q2 = 0, q3 = 0, spill = 0;
#pragma unroll
    for (int i = 0; i < 32; ++i) {
        int m = i * 64 + lane;
        qins(mkkey(distf(xb, m, xn0, xn1, xn2, sqn), m), q0, q1, q2, q3, spill);
    }

    __shared__ int cand[4][32];
    int C;

    unsigned lo = 0u, hi = 0xFFFFFFFFu;
#pragma unroll 1
    for (int it = 0; it < 32 && lo < hi; ++it) {
        unsigned span = hi - lo;
        unsigned mid  = lo + (span >> 1) + (span & 1);
        u64 M = (u64)mid << 32;
        int cnt = __popcll(__ballot(q0 >= M)) + __popcll(__ballot(q1 >= M))
                + __popcll(__ballot(q2 >= M)) + __popcll(__ballot(q3 >= M));
        if (cnt >= 26) lo = mid; else hi = mid - 1;
    }
    const u64 T64 = (u64)lo << 32;

    u64 b0 = __ballot(q0 >= T64), b1 = __ballot(q1 >= T64);
    u64 b2 = __ballot(q2 >= T64), b3 = __ballot(q3 >= T64);
    int n0 = __popcll(b0), n1 = __popcll(b1), n2 = __popcll(b2), n3 = __popcll(b3);
    C = n0 + n1 + n2 + n3;
    bool conflict = (__ballot(spill >= T64) != 0ull) || (C > 32);

    if (!conflict) {
        u64 ltm = (1ull << lane) - 1ull;
        if (q0 >= T64) cand[wid][__popcll(b0 & ltm)] = key2m(q0);
        if (q1 >= T64) cand[wid][n0 + __popcll(b1 & ltm)] = key2m(q1);
        if (q2 >= T64) cand[wid][n0 + n1 + __popcll(b2 & ltm)] = key2m(q2);
        if (q3 >= T64) cand[wid][n0 + n1 + n2 + __popcll(b3 & ltm)] = key2m(q3);
    } else {
        C = 26;
#pragma unroll 1
        for (int t = 0; t < 26; ++t) {
            u64 v = q0;
#pragma unroll
            for (int s = 1; s < 64; s <<= 1) {
                u64 ov = __shfl_xor(v, s);
                if (ov > v) v = ov;
            }
            if (lane == 0) cand[wid][t] = key2m(v);
            if (q0 == v) {
                q0 = q1; q1 = q2; q2 = q3; q3 = 0;
                if (!(q0 > spill)) {
                    q0 = q1 = q2 = q3 = 0; spill = 0;
                    for (int ii = 0; ii < 32; ++ii) {
                        int mr = ii * 64 + lane;
                        u64 kr = mkkey(distf(xb, mr, xn0, xn1, xn2, sqn), mr);
                        if (kr < v) qins(kr, q0, q1, q2, q3, spill);
                    }
                }
            }
        }
    }
    __syncthreads();

    int mm = (lane < C) ? cand[wid][lane] : 0;
    const double dxn0 = (double)xn0, dxn1 = (double)xn1, dxn2 = (double)xn2;
    const double dsqn = dxn0 * dxn0 + dxn1 * dxn1 + dxn2 * dxn2;
    double xm0 = (double)xb[mm], xm1 = (double)xb[NPT + mm], xm2 = (double)xb[2 * NPT + mm];
    double ddot = dxn0 * xm0 + dxn1 * xm1 + dxn2 * xm2;
    double dsqm = xm0 * xm0 + xm1 * xm1 + xm2 * xm2;
    double dd   = 2.0 * ddot - dsqn - dsqm;

    int rank = 0;
#pragma unroll 1
    for (int s = 0; s < C; ++s) {
        double ds = __shfl(dd, s);
        int    ms = __shfl(mm, s);
        if (ds > dd || (ds == dd && ms < mm)) ++rank;
    }
    if (lane < C && rank < KK) idxo[rank * BNP + r] = mm;   // transposed write
}

// ---------- conv1 (k-major pixels) + fused per-channel stats (replica banks) ----------
__global__ __launch_bounds__(256) void conv1_kernel(const float* __restrict__ x,
                                                    const int* __restrict__ idx,
                                                    const float* __restrict__ Wt,
                                                    f16* __restrict__ y,
                                                    float* __restrict__ strep) {
    const int tid = threadIdx.x, lane = tid & 63, wid = tid >> 6;
    int p = blockIdx.x * 256 + tid;
    int r = p & (BNP - 1);
    int n = r & 2047;
    int b = r >> 11;
    int m = idx[p];
    const float* xb = x + b * (3 * NPT);
    float f3 = xb[n], f4 = xb[NPT + n], f5 = xb[2 * NPT + n];
    float f0 = xb[m] - f3, f1 = xb[NPT + m] - f4, f2 = xb[2 * NPT + m] - f5;
    float fv[6] = { f0, f1, f2, f3, f4, f5 };

    float acc[64];
#pragma unroll
    for (int o = 0; o < 64; ++o) acc[o] = 0.f;
#pragma unroll
    for (int c = 0; c < 6; ++c) {
        float hv = fv[c];
#pragma unroll
        for (int o = 0; o < 64; ++o) acc[o] = fmaf(Wt[c * 64 + o], hv, acc[o]);
    }
    f16* yp = y + (size_t)p * 64;
#pragma unroll
    for (int o = 0; o < 64; ++o) yp[o] = (f16)acc[o];

    __shared__ float lsum[4][64], lsq[4][64];
#pragma unroll
    for (int o = 0; o < 64; ++o) {
        float s = acc[o], q = acc[o] * acc[o];
#pragma unroll
        for (int off = 32; off >= 1; off >>= 1) { s += __shfl_xor(s, off); q += __shfl_xor(q, off); }
        if (lane == 0) { lsum[wid][o] = s; lsq[wid][o] = q; }
    }
    __syncthreads();
    float* rep = strep + ((blockIdx.x & (NREP - 1)) << 10);
    if (tid < 64) {
        atomicAdd(rep + tid,       lsum[0][tid] + lsum[1][tid] + lsum[2][tid] + lsum[3][tid]);
        atomicAdd(rep + 512 + tid, lsq[0][tid] + lsq[1][tid] + lsq[2][tid] + lsq[3][tid]);
    }
}

// ---------- MFMA GEMM, input-BN applied on load, fused stats (L2, L3; replica banks) ----------
template<int CIN, int OBW>
__global__ __launch_bounds__(256) void conv_mfma_kernel(const f16* __restrict__ h,
                                                        const f16* __restrict__ W,
                                                        const float* __restrict__ scshIn,
                                                        f16* __restrict__ y,
                                                        float* __restrict__ strep) {
    constexpr int COUT = OBW * 64;
    const int tid = threadIdx.x, lane = tid & 63, wid = tid >> 6;
    const int lr = lane & 15, lg = lane >> 4;
    const int p0 = blockIdx.x * (256 / OBW) + (wid / OBW) * 64;
    const int ob = (wid & (OBW - 1)) * 64;

    f16x8 Bn[CIN / 32][4];
#pragma unroll
    for (int kt = 0; kt < CIN / 32; ++kt) {
        const int koff = kt * 32 + lg * 8;
        const float4 s0 = *(const float4*)(scshIn + koff);
        const float4 s1 = *(const float4*)(scshIn + koff + 4);
        const float4 h0 = *(const float4*)(scshIn + 512 + koff);
        const float4 h1 = *(const float4*)(scshIn + 512 + koff + 4);
        const float scr[8] = { s0.x, s0.y, s0.z, s0.w, s1.x, s1.y, s1.z, s1.w };
        const float shr[8] = { h0.x, h0.y, h0.z, h0.w, h1.x, h1.y, h1.z, h1.w };
#pragma unroll
        for (int pt = 0; pt < 4; ++pt) {
            f16x8 raw = *(const f16x8*)(h + (size_t)(p0 + pt * 16 + lr) * CIN + koff);
            f16x8 Bv;
#pragma unroll
            for (int e = 0; e < 8; ++e)
                Bv[e] = (f16)fmaxf(fmaf((float)raw[e], scr[e], shr[e]), 0.f);
            Bn[kt][pt] = Bv;
        }
    }

    f32x4 acc[4][4];
#pragma unroll
    for (int pt = 0; pt < 4; ++pt)
#pragma unroll
        for (int t = 0; t < 4; ++t) acc[pt][t] = (f32x4){0.f, 0.f, 0.f, 0.f};

#pragma unroll
    for (int kt = 0; kt < CIN / 32; ++kt) {
        const int koff = kt * 32 + lg * 8;
        f16x8 A[4];
#pragma unroll
        for (int t = 0; t < 4; ++t)
            A[t] = *(const f16x8*)(W + (size_t)(ob + 16 * t + lr) * CIN + koff);
#pragma unroll
        for (int pt = 0; pt < 4; ++pt)
#pragma unroll
            for (int t = 0; t < 4; ++t)
                acc[pt][t] = __builtin_amdgcn_mfma_f32_16x16x32_f16(A[t], Bn[kt][pt], acc[pt][t], 0, 0, 0);
    }
#pragma unroll
    for (int pt = 0; pt < 4; ++pt) {
        int px = p0 + pt * 16 + lr;
#pragma unroll
        for (int t = 0; t < 4; ++t) {
            f16x4 v;
            v[0] = (f16)acc[pt][t][0]; v[1] = (f16)acc[pt][t][1];
            v[2] = (f16)acc[pt][t][2]; v[3] = (f16)acc[pt][t][3];
            *(f16x4*)(y + (size_t)px * COUT + ob + 16 * t + 4 * lg) = v;
        }
    }
    __shared__ float lsum[4][64], lsq[4][64];
#pragma unroll
    for (int t = 0; t < 4; ++t)
#pragma unroll
        for (int j = 0; j < 4; ++j) {
            float s = acc[0][t][j] + acc[1][t][j] + acc[2][t][j] + acc[3][t][j];
            float q = acc[0][t][j] * acc[0][t][j] + acc[1][t][j] * acc[1][t][j]
                    + acc[2][t][j] * acc[2][t][j] + acc[3][t][j] * acc[3][t][j];
#pragma unroll
            for (int m2 = 1; m2 < 16; m2 <<= 1) { s += __shfl_xor(s, m2); q += __shfl_xor(q, m2); }
            if (lr == 0) { lsum[wid][16 * t + 4 * lg + j] = s; lsq[wid][16 * t + 4 * lg + j] = q; }
        }
    __syncthreads();
    float* rep = strep + ((blockIdx.x & (NREP - 1)) << 10);
    if (tid < COUT) {
        int obIdx = tid >> 6, c = tid & 63;
        float S = 0.f, Q = 0.f;
#pragma unroll
        for (int w = obIdx; w < 4; w += OBW) { S += lsum[w][c]; Q += lsq[w][c]; }
        atomicAdd(rep + tid, S);
        atomicAdd(rep + 512 + tid, Q);
    }
}

// ---------- conv4 (round-12 verified): async LDS-staged y3, register reductions ----------
__global__ __launch_bounds__(256) void conv4_fused_mfma(const f16* __restrict__ h,
                                                        const f16* __restrict__ W,
                                                        const float* __restrict__ scshIn,
                                                        float* __restrict__ strep,
                                                        f16* __restrict__ mx4,
                                                        f16* __restrict__ mn4,
                                                        f16* __restrict__ cat) {
    const int tid = threadIdx.x, lane = tid & 63, wid = tid >> 6;
    const int lr = lane & 15, lg = lane >> 4;
    const int r0 = blockIdx.x * 16;
    const int ob = wid * 64;

    __shared__ f16 sb[2][4][16][128];                // 32 KB

    f32x4 rmax[4], rmin[4], rsum[4], rsq[4];
#pragma unroll
    for (int t = 0; t < 4; ++t) {
        rmax[t] = (f32x4){-3.3e38f, -3.3e38f, -3.3e38f, -3.3e38f};
        rmin[t] = (f32x4){ 3.3e38f,  3.3e38f,  3.3e38f,  3.3e38f};
        rsum[t] = (f32x4){0.f, 0.f, 0.f, 0.f};
        rsq[t]  = (f32x4){0.f, 0.f, 0.f, 0.f};
    }
    f16x8 im[4];
#pragma unroll
    for (int kt = 0; kt < 4; ++kt)
#pragma unroll
        for (int e = 0; e < 8; ++e) im[kt][e] = (f16)0.f;

    auto STAGE = [&](int buf, int kc) {
        const f16* gk = h + ((size_t)(kc * 4 + wid) * BNP + r0) * 128;
#pragma unroll
        for (int i = 0; i < 4; ++i) {
            int rr = i * 4 + (lane >> 4);
            int cc = (lane & 15) ^ rr;               // pre-swizzled source chunk
            gload16(gk + (size_t)rr * 128 + cc * 8, &sb[buf][wid][i * 4][0]);
        }
    };

    STAGE(0, 0);
    __syncthreads();

    int cur = 0;
#pragma unroll 1
    for (int kc = 0; kc < 5; ++kc) {
        if (kc < 4) STAGE(cur ^ 1, kc + 1);

        f32x4 acc[4][4];
#pragma unroll
        for (int pt = 0; pt < 4; ++pt)
#pragma unroll
            for (int t = 0; t < 4; ++t) acc[pt][t] = (f32x4){0.f, 0.f, 0.f, 0.f};

#pragma unroll
        for (int kt = 0; kt < 4; ++kt) {
            const int koff = kt * 32 + lg * 8;
            const float4 s0 = *(const float4*)(scshIn + koff);
            const float4 s1 = *(const float4*)(scshIn + koff + 4);
            const float4 h0 = *(const float4*)(scshIn + 512 + koff);
            const float4 h1 = *(const float4*)(scshIn + 512 + koff + 4);
            const float scr[8] = { s0.x, s0.y, s0.z, s0.w, s1.x, s1.y, s1.z, s1.w };
            const float shr[8] = { h0.x, h0.y, h0.z, h0.w, h1.x, h1.y, h1.z, h1.w };
            f16x8 A[4];
#pragma unroll
            for (int t = 0; t < 4; ++t)
                A[t] = *(const f16x8*)(W + (size_t)(ob + 16 * t + lr) * 128 + koff);
            f16x8 Bv[4];
#pragma unroll
            for (int pt = 0; pt < 4; ++pt) {
                int cpos = (kt * 4 + lg) ^ lr;
                f16x8 raw = *(const f16x8*)(&sb[cur][pt][lr][cpos * 8]);
                f16x8 Bn;
#pragma unroll
                for (int e = 0; e < 8; ++e)
                    Bn[e] = (f16)fmaxf(fmaf((float)raw[e], scr[e], shr[e]), 0.f);
                Bv[pt] = Bn;
            }
#pragma unroll
            for (int pt = 0; pt < 4; ++pt)
#pragma unroll
                for (int e = 0; e < 8; ++e)
                    im[kt][e] = (Bv[pt][e] > im[kt][e]) ? Bv[pt][e] : im[kt][e];
#pragma unroll
            for (int pt = 0; pt < 4; ++pt)
#pragma unroll
                for (int t = 0; t < 4; ++t)
                    acc[pt][t] = __builtin_amdgcn_mfma_f32_16x16x32_f16(A[t], Bv[pt], acc[pt][t], 0, 0, 0);
        }
#pragma unroll
        for (int pt = 0; pt < 4; ++pt)
#pragma unroll
            for (int t = 0; t < 4; ++t)
#pragma unroll
                for (int j = 0; j < 4; ++j) {
                    float v = acc[pt][t][j];
                    rmax[t][j] = fmaxf(rmax[t][j], v);
                    rmin[t][j] = fminf(rmin[t][j], v);
                    rsum[t][j] += v;
                    rsq[t][j]  += v * v;
                }
        __syncthreads();
        cur ^= 1;
    }

    if (wid == 0) {
#pragma unroll
        for (int kt = 0; kt < 4; ++kt)
            *(f16x8*)(cat + (size_t)(r0 + lr) * 512 + 128 + kt * 32 + lg * 8) = im[kt];
    }
#pragma unroll
    for (int t = 0; t < 4; ++t) {
        f16x4 vx, vn;
#pragma unroll
        for (int j = 0; j < 4; ++j) { vx[j] = (f16)rmax[t][j]; vn[j] = (f16)rmin[t][j]; }
        size_t base = (size_t)(r0 + lr) * 256 + ob + 16 * t + 4 * lg;
        *(f16x4*)(mx4 + base) = vx;
        *(f16x4*)(mn4 + base) = vn;
    }
    float* rep = strep + ((blockIdx.x & (NREP - 1)) << 10);
#pragma unroll
    for (int t = 0; t < 4; ++t)
#pragma unroll
        for (int j = 0; j < 4; ++j) {
            float s = rsum[t][j], q = rsq[t][j];
#pragma unroll
            for (int m2 = 1; m2 < 16; m2 <<= 1) { s += __shfl_xor(s, m2); q += __shfl_xor(q, m2); }
            if (lr == 0) {
                atomicAdd(rep + ob + 16 * t + 4 * lg + j, s);
                atomicAdd(rep + 512 + ob + 16 * t + 4 * lg + j, q);
            }
        }
}

// ---------- conv4 epilogue: BN+ReLU on max/min (monotone commute) -> cat[256:512) ----------
__global__ __launch_bounds__(256) void cat4_kernel(const f16* __restrict__ mx4,
                                                   const f16* __restrict__ mn4,
                                                   const float* __restrict__ scsh,
                                                   f16* __restrict__ cat) {
    int i = blockIdx.x * 256 + threadIdx.x;
    int r = i >> 8, ch = i & 255;
    float sc = scsh[ch], sh = scsh[512 + ch];
    float v  = (sc > 0.f) ? (float)mx4[i] : (float)mn4[i];
    cat[(size_t)r * 512 + 256 + ch] = (f16)fmaxf(fmaf(v, sc, sh), 0.f);
}

// ---------- conv5: waves share px, differ in ob (replica-bank stats) ----------
__global__ __launch_bounds__(256) void conv5_mfma(const f16* __restrict__ cat,
                                                  const f16* __restrict__ W,
                                                  float* __restrict__ out,
                                                  float* __restrict__ strep) {
    const int tid = threadIdx.x;
    const int lane = tid & 63, wid = tid >> 6;
    const int lr = lane & 15, lg = lane >> 4;
    const int p0 = blockIdx.x * 64;
    const int ob = blockIdx.y * 256 + wid * 64;

    f32x4 acc[4][4];
#pragma unroll
    for (int pt = 0; pt < 4; ++pt)
#pragma unroll
        for (int t = 0; t < 4; ++t) acc[pt][t] = (f32x4){0.f, 0.f, 0.f, 0.f};

#pragma unroll
    for (int kt = 0; kt < 16; ++kt) {
        const int koff = kt * 32 + lg * 8;
        f16x8 A[4];
#pragma unroll
        for (int t = 0; t < 4; ++t)
            A[t] = *(const f16x8*)(W + (size_t)(ob + 16 * t + lr) * 512 + koff);
#pragma unroll
        for (int pt = 0; pt < 4; ++pt) {
            f16x8 B = *(const f16x8*)(cat + (size_t)(p0 + pt * 16 + lr) * 512 + koff);
#pragma unroll
            for (int t = 0; t < 4; ++t)
                acc[pt][t] = __builtin_amdgcn_mfma_f32_16x16x32_f16(A[t], B, acc[pt][t], 0, 0, 0);
        }
    }
#pragma unroll
    for (int pt = 0; pt < 4; ++pt) {
        int px = p0 + pt * 16 + lr;
        int b = px >> 11, n = px & 2047;
#pragma unroll
        for (int t = 0; t < 4; ++t) {
#pragma unroll
            for (int j = 0; j < 4; ++j) {
                int o = ob + 16 * t + 4 * lg + j;
                out[((size_t)(b * 512 + o)) * 2048 + n] = acc[pt][t][j];
            }
        }
    }
    __shared__ float lsum[4][64], lsq[4][64];
#pragma unroll
    for (int t = 0; t < 4; ++t)
#pragma unroll
        for (int j = 0; j < 4; ++j) {
            float s = acc[0][t][j] + acc[1][t][j] + acc[2][t][j] + acc[3][t][j];
            float q = acc[0][t][j] * acc[0][t][j] + acc[1][t][j] * acc[1][t][j]
                    + acc[2][t][j] * acc[2][t][j] + acc[3][t][j] * acc[3][t][j];
#pragma unroll
            for (int m2 = 1; m2 < 16; m2 <<= 1) { s += __shfl_xor(s, m2); q += __shfl_xor(q, m2); }
            if (lr == 0) { lsum[wid][16 * t + 4 * lg + j] = s; lsq[wid][16 * t + 4 * lg + j] = q; }
        }
    __syncthreads();
    float* rep = strep + ((blockIdx.x & (NREP - 1)) << 10);
    if (tid < 256) {
        int w = tid >> 6, c = tid & 63;
        atomicAdd(rep + blockIdx.y * 256 + tid, lsum[w][c]);
        atomicAdd(rep + 512 + blockIdx.y * 256 + tid, lsq[w][c]);
    }
}

// ---------- BN finalize: sums NREP replica banks, emits scale|shift ----------
__global__ void finalize_kernel(const float* __restrict__ strep, const float* __restrict__ g,
                                const float* __restrict__ bb, float* __restrict__ scsh,
                                int C, float invM) {
    int c = threadIdx.x;
    if (c < C) {
        float s = 0.f, q = 0.f;
#pragma unroll 4
        for (int rr = 0; rr < NREP; ++rr) {
            s += strep[rr * 1024 + c];
            q += strep[rr * 1024 + 512 + c];
        }
        float mean = s * invM;
        float var  = q * invM - mean * mean;
        float istd = rsqrtf(var + EPS_BN);
        float sc   = g[c] * istd;
        scsh[c]       = sc;
        scsh[512 + c] = bb[c] - mean * sc;
    }
}

// ---------- vectorized catmax (k-major): f16x8 coalesced, BN+max over k -> cat ----------
template<int C>
__global__ __launch_bounds__(256) void catmax_vec(const f16* __restrict__ y,
                                                  const float* __restrict__ scsh,
                                                  f16* __restrict__ cat, int coff) {
    constexpr int CB = C / 8;
    int i  = blockIdx.x * 256 + threadIdx.x;
    int r  = i / CB;
    int cc = (i - r * CB) * 8;
    float sc[8], sh[8];
#pragma unroll
    for (int e = 0; e < 8; ++e) { sc[e] = scsh[cc + e]; sh[e] = scsh[512 + cc + e]; }
    float mx[8];
#pragma unroll
    for (int e = 0; e < 8; ++e) mx[e] = -3.3e38f;
#pragma unroll
    for (int k = 0; k < KK; ++k) {
        f16x8 v = *(const f16x8*)(y + ((size_t)k * BNP + r) * C + cc);
#pragma unroll
        for (int e = 0; e < 8; ++e)
            mx[e] = fmaxf(mx[e], fmaf((float)v[e], sc[e], sh[e]));
    }
    f16x8 o;
#pragma unroll
    for (int e = 0; e < 8; ++e) o[e] = (f16)fmaxf(mx[e], 0.f);
    *(f16x8*)(cat + (size_t)r * 512 + coff + cc) = o;
}

// ---------- final normalize + ReLU on conv5 output in place ----------
__global__ __launch_bounds__(256) void norm5_kernel(float* __restrict__ out,
                                                    const float* __restrict__ scsh) {
    int o = blockIdx.y;
    int r = blockIdx.x * 256 + threadIdx.x;
    int b = r >> 11, n = r & 2047;
    float sc = scsh[o], sh = scsh[512 + o];
    size_t i = ((size_t)(b * 512 + o)) * 2048 + n;
    float v = fmaf(out[i], sc, sh);
    out[i] = v > 0.f ? v : 0.f;
}

extern "C" void kernel_launch(void* const* d_in, const int* in_sizes, int n_in,
                              void* d_out, int out_size, void* d_ws, size_t ws_size,
                              hipStream_t stream) {
    float* out = (float*)d_out;
    if (ws_size < WS_NEED) {
        marker_kernel<<<1, 64, 0, stream>>>(out, 1000.0f + (float)(ws_size >> 20));
        return;
    }

    const float* x  = (const float*)d_in[0];
    const float* W1 = (const float*)d_in[1];
    const float* g1 = (const float*)d_in[2];
    const float* b1 = (const float*)d_in[3];
    const float* W2 = (const float*)d_in[4];
    const float* g2 = (const float*)d_in[5];
    const float* b2 = (const float*)d_in[6];
    const float* W3 = (const float*)d_in[7];
    const float* g3 = (const float*)d_in[8];
    const float* b3 = (const float*)d_in[9];
    const float* W4 = (const float*)d_in[10];
    const float* g4 = (const float*)d_in[11];
    const float* b4 = (const float*)d_in[12];
    const float* W5 = (const float*)d_in[13];
    const float* g5 = (const float*)d_in[14];
    const float* b5 = (const float*)d_in[15];

    char*  ws    = (char*)d_ws;
    int*   idx   = (int*)(ws + OFF_IDX);
    float* wt1   = (float*)(ws + OFF_WT1);
    f16*   wh2   = (f16*)(ws + OFF_WH2);
    f16*   wh3   = (f16*)(ws + OFF_WH3);
    f16*   wh4   = (f16*)(ws + OFF_WH4);
    f16*   wh5   = (f16*)(ws + OFF_WH5);
    float* scsh  = (float*)(ws + OFF_SS);
    f16*   cat   = (f16*)(ws + OFF_CAT);
    f16*   y1    = (f16*)(ws + OFF_Y1);
    f16*   y2    = (f16*)(ws + OFF_Y2);
    f16*   y3    = (f16*)(ws + OFF_Y3);
    f16*   mx4   = (f16*)(ws + OFF_Y2);                          // y2 dead at L4
    f16*   mn4   = (f16*)(ws + OFF_Y2 + (size_t)BNP * 256 * 2);
    float* strep = (float*)(ws + OFF_REP);                       // [NREP][1024]

    constexpr size_t REP_BYTES = (size_t)NREP * 1024 * 4;
    hipMemsetAsync(strep, 0, REP_BYTES, stream);

    prep_weights<<<1024, 256, 0, stream>>>(W1, W2, W3, W4, W5, wt1, wh2, wh3, wh4, wh5);
    knn_kernel<<<4096, 256, 0, stream>>>(x, idx);

    const float invM  = 1.0f / (float)PT;
    const float invM5 = 1.0f / (float)BNP;

    // L1: 6 -> 64 (raw y1, stats fused into replica banks)
    conv1_kernel<<<PT / 256, 256, 0, stream>>>(x, idx, wt1, y1, strep);
    finalize_kernel<<<1, 512, 0, stream>>>(strep, g1, b1, scsh + 0, 64, invM);
    hipMemsetAsync(strep, 0, REP_BYTES, stream);
    catmax_vec<64><<<BNP * 8 / 256, 256, 0, stream>>>(y1, scsh + 0, cat, 0);

    // L2: 64 -> 64 (BN1 on load; stats fused)
    conv_mfma_kernel<64, 1><<<PT / 256, 256, 0, stream>>>(y1, wh2, scsh + 0, y2, strep);
    finalize_kernel<<<1, 512, 0, stream>>>(strep, g2, b2, scsh + 1024, 64, invM);
    hipMemsetAsync(strep, 0, REP_BYTES, stream);
    catmax_vec<64><<<BNP * 8 / 256, 256, 0, stream>>>(y2, scsh + 1024, cat, 64);

    // L3: 64 -> 128 (BN2 on load; OBW=2; clobbers dead y1; stats fused)
    conv_mfma_kernel<64, 2><<<PT / 128, 256, 0, stream>>>(y2, wh3, scsh + 1024, y3, strep);
    finalize_kernel<<<1, 512, 0, stream>>>(strep, g3, b3, scsh + 2048, 128, invM);
    hipMemsetAsync(strep, 0, REP_BYTES, stream);

    // L4: 128 -> 256, async-LDS-staged; fused: stats4 + raw max/min + INPUT catmax
    conv4_fused_mfma<<<BNP / 16, 256, 0, stream>>>(y3, wh4, scsh + 2048, strep, mx4, mn4, cat);
    finalize_kernel<<<1, 512, 0, stream>>>(strep, g4, b4, scsh + 3072, 256, invM);
    hipMemsetAsync(strep, 0, REP_BYTES, stream);
    cat4_kernel<<<BNP, 256, 0, stream>>>(mx4, mn4, scsh + 3072, cat);

    // L5: 512 -> 512 on cat -> d_out raw (stats fused)
    conv5_mfma<<<dim3(BNP / 64, 2), 256, 0, stream>>>(cat, wh5, out, strep);
    finalize_kernel<<<1, 512, 0, stream>>>(strep, g5, b5, scsh + 4096, 512, invM5);
    norm5_kernel<<<dim3(BNP / 256, 512), 256, 0, stream>>>(out, scsh + 4096);
}

// Round 15
// 401.817 us; speedup vs baseline: 1.6166x; 1.0329x over previous
//
#include <hip/hip_runtime.h>
#include <hip/hip_bf16.h>

typedef _Float16 f16;
typedef _Float16 f16x8 __attribute__((ext_vector_type(8)));
typedef _Float16 f16x4 __attribute__((ext_vector_type(4)));
typedef float    f32x4 __attribute__((ext_vector_type(4)));
typedef unsigned long long u64;

constexpr int NB  = 8;
constexpr int NPT = 2048;
constexpr int KK  = 20;
constexpr int PT  = NB * NPT * KK;   // 327680 pixels, layers 1-4
constexpr int BNP = NB * NPT;        // 16384 points (= 2^14)
constexpr float EPS_BN = 1e-5f;
constexpr int NREP = 64;             // stats replica banks

// ---------- workspace layout (bytes) ----------
constexpr size_t OFF_IDX = 0;                                    // int [KK][BNP] (transposed)
constexpr size_t OFF_WT1 = OFF_IDX + (size_t)BNP * KK * 4;
constexpr size_t OFF_WH2 = OFF_WT1 + 384 * 4;
constexpr size_t OFF_WH3 = OFF_WH2 + 4096 * 2;
constexpr size_t OFF_WH4 = OFF_WH3 + 8192 * 2;
constexpr size_t OFF_WH5 = OFF_WH4 + 32768 * 2;
constexpr size_t OFF_ST  = OFF_WH5 + 262144 * 2;                 // scshH f16 [5][1024] (10 KB of 20)
constexpr size_t OFF_SS  = OFF_ST + 5 * 1024 * 4;
constexpr size_t OFF_CAT = OFF_SS + 5 * 1024 * 4;                // f16 [BNP][512]
constexpr size_t OFF_Y3  = OFF_CAT + (size_t)BNP * 512 * 2;      // f16 [PT][128] (k-major pixels)
constexpr size_t OFF_Y1  = OFF_Y3 + (size_t)PT * 64 * 2;         // aliases upper half of y3
constexpr size_t OFF_Y2  = OFF_Y3 + (size_t)PT * 128 * 2;        // f16 [PT][64]; at L4: mx4|mn4
constexpr size_t OFF_REP = OFF_Y2 + (size_t)PT * 64 * 2;         // f32 [NREP][1024] = 256 KB
constexpr size_t WS_NEED = OFF_REP + (size_t)NREP * 1024 * 4;    // 144,836,096 B

// ---------- diagnostic ----------
__global__ void marker_kernel(float* __restrict__ out, float v) {
    if (threadIdx.x == 0 && blockIdx.x == 0) out[0] = v;
}

// ---------- async global->LDS (wave-uniform LDS base + lane*16B dest) ----------
__device__ __forceinline__ void gload16(const f16* g, f16* ldsbase) {
    __builtin_amdgcn_global_load_lds(
        (const __attribute__((address_space(1))) void*)g,
        (__attribute__((address_space(3))) void*)ldsbase, 16, 0, 0);
}

// ---------- weight prep ----------
__global__ __launch_bounds__(256) void prep_weights(
        const float* __restrict__ W1, const float* __restrict__ W2,
        const float* __restrict__ W3, const float* __restrict__ W4,
        const float* __restrict__ W5,
        float* __restrict__ wt1, f16* __restrict__ wh2, f16* __restrict__ wh3,
        f16* __restrict__ wh4, f16* __restrict__ wh5) {
    int i = blockIdx.x * 256 + threadIdx.x;
    if (i < 384)    { int o = i / 6, c = i - o * 6; wt1[c * 64 + o] = W1[i]; }
    if (i < 4096)   wh2[i] = (f16)W2[i];
    if (i < 8192)   wh3[i] = (f16)W3[i];
    if (i < 32768)  wh4[i] = (f16)W4[i];
    if (i < 262144) wh5[i] = (f16)W5[i];
}

// ---------- kNN v6: LDS sq-table + dual 4-deep queues + bisection + f64 refine ----------
__device__ __forceinline__ u64 mkkey(float d, int m) {
    unsigned u = __float_as_uint(d);
    u = (u & 0x80000000u) ? ~u : (u | 0x80000000u);
    return ((u64)u << 32) | (unsigned)(2047 - m);
}
__device__ __forceinline__ int key2m(u64 k) { return 2047 - (int)(k & 0xFFFFFFFFull); }

__device__ __forceinline__ void qins(u64 k, u64& q0, u64& q1, u64& q2, u64& q3, u64& spill) {
    bool c0 = k > q0, c1 = k > q1, c2 = k > q2, c3 = k > q3;
    u64 drop = c3 ? q3 : k;
    spill = spill > drop ? spill : drop;
    q3 = c2 ? q2 : (c3 ? k : q3);
    q2 = c1 ? q1 : (c2 ? k : q2);
    q1 = c0 ? q0 : (c1 ? k : q1);
    q0 = c0 ? k  : q0;
}

__global__ __launch_bounds__(256) void knn_kernel(const float* __restrict__ x,
                                                  int* __restrict__ idxo) {
    const int tid  = threadIdx.x;
    const int lane = tid & 63;
    const int wid  = tid >> 6;
    const int r    = blockIdx.x * 4 + wid;   // 4 rows/block, all in same batch (4 | 2048)
    const int b    = r >> 11;
    const int n    = r & 2047;
    const float* xb = x + b * (3 * NPT);

    __shared__ float sqs[NPT];               // 8 KB, shared by the block's 4 rows
    __shared__ int   cand[4][32];
#pragma unroll
    for (int i = 0; i < NPT / 256; ++i) {
        int m = i * 256 + tid;
        float a0 = xb[m], a1 = xb[NPT + m], a2 = xb[2 * NPT + m];
        sqs[m] = __fadd_rn(__fadd_rn(__fmul_rn(a0, a0), __fmul_rn(a1, a1)),
                           __fmul_rn(a2, a2));
    }
    __syncthreads();

    const float xn0 = xb[n], xn1 = xb[NPT + n], xn2 = xb[2 * NPT + n];
    const float sqn = sqs[n];

    // pinned-rounding distance: bit-identical at every call site
    auto dist2 = [&](int m) -> float {
        float dot = __fmaf_rn(xn0, xb[m],
                    __fmaf_rn(xn1, xb[NPT + m],
                    __fmul_rn(xn2, xb[2 * NPT + m])));
        return __fsub_rn(__fsub_rn(__fmul_rn(2.f, dot), sqn), sqs[m]);
    };

    // two independent insertion chains (ILP 2), 16 candidates each
    u64 qa0 = 0, qa1 = 0, qa2 = 0, qa3 = 0, sA = 0;
    u64 qb0 = 0, qb1 = 0, qb2 = 0, qb3 = 0, sB = 0;
#pragma unroll
    for (int i = 0; i < 16; ++i) {
        int ma = i * 64 + lane;
        int mb = 1024 + ma;
        float da = dist2(ma);
        float db = dist2(mb);
        qins(mkkey(da, ma), qa0, qa1, qa2, qa3, sA);
        qins(mkkey(db, mb), qb0, qb1, qb2, qb3, sB);
    }
    // merge: top4(top4A ∪ top4B) = lane's top-4 of all 32; spill bounds the rest
    u64 spill = sA > sB ? sA : sB;
    qins(qb0, qa0, qa1, qa2, qa3, spill);
    qins(qb1, qa0, qa1, qa2, qa3, spill);
    qins(qb2, qa0, qa1, qa2, qa3, spill);
    qins(qb3, qa0, qa1, qa2, qa3, spill);
    u64 q0 = qa0, q1 = qa1, q2 = qa2, q3 = qa3;

    int C;
    unsigned lo = 0u, hi = 0xFFFFFFFFu;
#pragma unroll 1
    for (int it = 0; it < 32 && lo < hi; ++it) {
        unsigned span = hi - lo;
        unsigned mid  = lo + (span >> 1) + (span & 1);
        u64 M = (u64)mid << 32;
        int cnt = __popcll(__ballot(q0 >= M)) + __popcll(__ballot(q1 >= M))
                + __popcll(__ballot(q2 >= M)) + __popcll(__ballot(q3 >= M));
        if (cnt >= 26) lo = mid; else hi = mid - 1;
    }
    const u64 T64 = (u64)lo << 32;

    u64 b0 = __ballot(q0 >= T64), b1 = __ballot(q1 >= T64);
    u64 b2 = __ballot(q2 >= T64), b3 = __ballot(q3 >= T64);
    int n0 = __popcll(b0), n1 = __popcll(b1), n2 = __popcll(b2), n3 = __popcll(b3);
    C = n0 + n1 + n2 + n3;
    bool conflict = (__ballot(spill >= T64) != 0ull) || (C > 32);

    if (!conflict) {
        u64 ltm = (1ull << lane) - 1ull;
        if (q0 >= T64) cand[wid][__popcll(b0 & ltm)] = key2m(q0);
        if (q1 >= T64) cand[wid][n0 + __popcll(b1 & ltm)] = key2m(q1);
        if (q2 >= T64) cand[wid][n0 + n1 + __popcll(b2 & ltm)] = key2m(q2);
        if (q3 >= T64) cand[wid][n0 + n1 + n2 + __popcll(b3 & ltm)] = key2m(q3);
    } else {
        C = 26;
#pragma unroll 1
        for (int t = 0; t < 26; ++t) {
            u64 v = q0;
#pragma unroll
            for (int s = 1; s < 64; s <<= 1) {
                u64 ov = __shfl_xor(v, s);
                if (ov > v) v = ov;
            }
            if (lane == 0) cand[wid][t] = key2m(v);
            if (q0 == v) {
                q0 = q1; q1 = q2; q2 = q3; q3 = 0;
                if (!(q0 > spill)) {                 // rescue: rebuild below last pop
                    q0 = q1 = q2 = q3 = 0; spill = 0;
                    for (int ii = 0; ii < 32; ++ii) {
                        int mr = ii * 64 + lane;
                        u64 kr = mkkey(dist2(mr), mr);
                        if (kr < v) qins(kr, q0, q1, q2, q3, spill);
                    }
                }
            }
        }
    }
    __syncthreads();

    int mm = (lane < C) ? cand[wid][lane] : 0;
    const double dxn0 = (double)xn0, dxn1 = (double)xn1, dxn2 = (double)xn2;
    const double dsqn = dxn0 * dxn0 + dxn1 * dxn1 + dxn2 * dxn2;
    double xm0 = (double)xb[mm], xm1 = (double)xb[NPT + mm], xm2 = (double)xb[2 * NPT + mm];
    double ddot = dxn0 * xm0 + dxn1 * xm1 + dxn2 * xm2;
    double dsqm = xm0 * xm0 + xm1 * xm1 + xm2 * xm2;
    double dd   = 2.0 * ddot - dsqn - dsqm;

    int rank = 0;
#pragma unroll 1
    for (int s = 0; s < C; ++s) {
        double ds = __shfl(dd, s);
        int    ms = __shfl(mm, s);
        if (ds > dd || (ds == dd && ms < mm)) ++rank;
    }
    if (lane < C && rank < KK) idxo[rank * BNP + r] = mm;   // transposed write
}

// ---------- conv1 (k-major pixels) + fused per-channel stats (replica banks) ----------
__global__ __launch_bounds__(256) void conv1_kernel(const float* __restrict__ x,
                                                    const int* __restrict__ idx,
                                                    const float* __restrict__ Wt,
                                                    f16* __restrict__ y,
                                                    float* __restrict__ strep) {
    const int tid = threadIdx.x, lane = tid & 63, wid = tid >> 6;
    int p = blockIdx.x * 256 + tid;
    int r = p & (BNP - 1);
    int n = r & 2047;
    int b = r >> 11;
    int m = idx[p];
    const float* xb = x + b * (3 * NPT);
    float f3 = xb[n], f4 = xb[NPT + n], f5 = xb[2 * NPT + n];
    float f0 = xb[m] - f3, f1 = xb[NPT + m] - f4, f2 = xb[2 * NPT + m] - f5;
    float fv[6] = { f0, f1, f2, f3, f4, f5 };

    float acc[64];
#pragma unroll
    for (int o = 0; o < 64; ++o) acc[o] = 0.f;
#pragma unroll
    for (int c = 0; c < 6; ++c) {
        float hv = fv[c];
#pragma unroll
        for (int o = 0; o < 64; ++o) acc[o] = fmaf(Wt[c * 64 + o], hv, acc[o]);
    }
    f16* yp = y + (size_t)p * 64;
#pragma unroll
    for (int o = 0; o < 64; ++o) yp[o] = (f16)acc[o];

    __shared__ float lsum[4][64], lsq[4][64];
#pragma unroll
    for (int o = 0; o < 64; ++o) {
        float s = acc[o], q = acc[o] * acc[o];
#pragma unroll
        for (int off = 32; off >= 1; off >>= 1) { s += __shfl_xor(s, off); q += __shfl_xor(q, off); }
        if (lane == 0) { lsum[wid][o] = s; lsq[wid][o] = q; }
    }
    __syncthreads();
    float* rep = strep + ((blockIdx.x & (NREP - 1)) << 10);
    if (tid < 64) {
        atomicAdd(rep + tid,       lsum[0][tid] + lsum[1][tid] + lsum[2][tid] + lsum[3][tid]);
        atomicAdd(rep + 512 + tid, lsq[0][tid] + lsq[1][tid] + lsq[2][tid] + lsq[3][tid]);
    }
}

// ---------- MFMA GEMM, f16 BN-on-load, fused stats (L2, L3; replica banks) ----------
template<int CIN, int OBW>
__global__ __launch_bounds__(256) void conv_mfma_kernel(const f16* __restrict__ h,
                                                        const f16* __restrict__ W,
                                                        const f16* __restrict__ scshH,
                                                        f16* __restrict__ y,
                                                        float* __restrict__ strep) {
    constexpr int COUT = OBW * 64;
    const int tid = threadIdx.x, lane = tid & 63, wid = tid >> 6;
    const int lr = lane & 15, lg = lane >> 4;
    const int p0 = blockIdx.x * (256 / OBW) + (wid / OBW) * 64;
    const int ob = (wid & (OBW - 1)) * 64;

    f16x8 Bn[CIN / 32][4];
#pragma unroll
    for (int kt = 0; kt < CIN / 32; ++kt) {
        const int koff = kt * 32 + lg * 8;
        f16x8 scf = *(const f16x8*)(scshH + koff);
        f16x8 shf = *(const f16x8*)(scshH + 512 + koff);
#pragma unroll
        for (int pt = 0; pt < 4; ++pt) {
            f16x8 raw = *(const f16x8*)(h + (size_t)(p0 + pt * 16 + lr) * CIN + koff);
            f16x8 t = raw * scf + shf;
            f16x8 Bv;
#pragma unroll
            for (int e = 0; e < 8; ++e)
                Bv[e] = t[e] > (f16)0.f ? t[e] : (f16)0.f;
            Bn[kt][pt] = Bv;
        }
    }

    f32x4 acc[4][4];
#pragma unroll
    for (int pt = 0; pt < 4; ++pt)
#pragma unroll
        for (int t = 0; t < 4; ++t) acc[pt][t] = (f32x4){0.f, 0.f, 0.f, 0.f};

#pragma unroll
    for (int kt = 0; kt < CIN / 32; ++kt) {
        const int koff = kt * 32 + lg * 8;
        f16x8 A[4];
#pragma unroll
        for (int t = 0; t < 4; ++t)
            A[t] = *(const f16x8*)(W + (size_t)(ob + 16 * t + lr) * CIN + koff);
#pragma unroll
        for (int pt = 0; pt < 4; ++pt)
#pragma unroll
            for (int t = 0; t < 4; ++t)
                acc[pt][t] = __builtin_amdgcn_mfma_f32_16x16x32_f16(A[t], Bn[kt][pt], acc[pt][t], 0, 0, 0);
    }
#pragma unroll
    for (int pt = 0; pt < 4; ++pt) {
        int px = p0 + pt * 16 + lr;
#pragma unroll
        for (int t = 0; t < 4; ++t) {
            f16x4 v;
            v[0] = (f16)acc[pt][t][0]; v[1] = (f16)acc[pt][t][1];
            v[2] = (f16)acc[pt][t][2]; v[3] = (f16)acc[pt][t][3];
            *(f16x4*)(y + (size_t)px * COUT + ob + 16 * t + 4 * lg) = v;
        }
    }
    __shared__ float lsum[4][64], lsq[4][64];
#pragma unroll
    for (int t = 0; t < 4; ++t)
#pragma unroll
        for (int j = 0; j < 4; ++j) {
            float s = acc[0][t][j] + acc[1][t][j] + acc[2][t][j] + acc[3][t][j];
            float q = acc[0][t][j] * acc[0][t][j] + acc[1][t][j] * acc[1][t][j]
                    + acc[2][t][j] * acc[2][t][j] + acc[3][t][j] * acc[3][t][j];
#pragma unroll
            for (int m2 = 1; m2 < 16; m2 <<= 1) { s += __shfl_xor(s, m2); q += __shfl_xor(q, m2); }
            if (lr == 0) { lsum[wid][16 * t + 4 * lg + j] = s; lsq[wid][16 * t + 4 * lg + j] = q; }
        }
    __syncthreads();
    float* rep = strep + ((blockIdx.x & (NREP - 1)) << 10);
    if (tid < COUT) {
        int obIdx = tid >> 6, c = tid & 63;
        float S = 0.f, Q = 0.f;
#pragma unroll
        for (int w = obIdx; w < 4; w += OBW) { S += lsum[w][c]; Q += lsq[w][c]; }
        atomicAdd(rep + tid, S);
        atomicAdd(rep + 512 + tid, Q);
    }
}

// ---------- conv4: async LDS-staged y3, f16 BN-on-load, register reductions ----------
__global__ __launch_bounds__(256) void conv4_fused_mfma(const f16* __restrict__ h,
                                                        const f16* __restrict__ W,
                                                        const f16* __restrict__ scshH,
                                                        float* __restrict__ strep,
                                                        f16* __restrict__ mx4,
                                                        f16* __restrict__ mn4,
                                                        f16* __restrict__ cat) {
    const int tid = threadIdx.x, lane = tid & 63, wid = tid >> 6;
    const int lr = lane & 15, lg = lane >> 4;
    const int r0 = blockIdx.x * 16;
    const int ob = wid * 64;

    __shared__ f16 sb[2][4][16][128];                // 32 KB

    f32x4 rmax[4], rmin[4], rsum[4], rsq[4];
#pragma unroll
    for (int t = 0; t < 4; ++t) {
        rmax[t] = (f32x4){-3.3e38f, -3.3e38f, -3.3e38f, -3.3e38f};
        rmin[t] = (f32x4){ 3.3e38f,  3.3e38f,  3.3e38f,  3.3e38f};
        rsum[t] = (f32x4){0.f, 0.f, 0.f, 0.f};
        rsq[t]  = (f32x4){0.f, 0.f, 0.f, 0.f};
    }
    f16x8 im[4];
#pragma unroll
    for (int kt = 0; kt < 4; ++kt)
#pragma unroll
        for (int e = 0; e < 8; ++e) im[kt][e] = (f16)0.f;

    auto STAGE = [&](int buf, int kc) {
        const f16* gk = h + ((size_t)(kc * 4 + wid) * BNP + r0) * 128;
#pragma unroll
        for (int i = 0; i < 4; ++i) {
            int rr = i * 4 + (lane >> 4);
            int cc = (lane & 15) ^ rr;               // pre-swizzled source chunk
            gload16(gk + (size_t)rr * 128 + cc * 8, &sb[buf][wid][i * 4][0]);
        }
    };

    STAGE(0, 0);
    __syncthreads();

    int cur = 0;
#pragma unroll 1
    for (int kc = 0; kc < 5; ++kc) {
        if (kc < 4) STAGE(cur ^ 1, kc + 1);

        f32x4 acc[4][4];
#pragma unroll
        for (int pt = 0; pt < 4; ++pt)
#pragma unroll
            for (int t = 0; t < 4; ++t) acc[pt][t] = (f32x4){0.f, 0.f, 0.f, 0.f};

#pragma unroll
        for (int kt = 0; kt < 4; ++kt) {
            const int koff = kt * 32 + lg * 8;
            f16x8 scf = *(const f16x8*)(scshH + koff);
            f16x8 shf = *(const f16x8*)(scshH + 512 + koff);
            f16x8 A[4];
#pragma unroll
            for (int t = 0; t < 4; ++t)
                A[t] = *(const f16x8*)(W + (size_t)(ob + 16 * t + lr) * 128 + koff);
            f16x8 Bv[4];
#pragma unroll
            for (int pt = 0; pt < 4; ++pt) {
                int cpos = (kt * 4 + lg) ^ lr;
                f16x8 raw = *(const f16x8*)(&sb[cur][pt][lr][cpos * 8]);
                f16x8 t = raw * scf + shf;
                f16x8 Bn;
#pragma unroll
                for (int e = 0; e < 8; ++e)
                    Bn[e] = t[e] > (f16)0.f ? t[e] : (f16)0.f;
                Bv[pt] = Bn;
            }
#pragma unroll
            for (int pt = 0; pt < 4; ++pt)
#pragma unroll
                for (int e = 0; e < 8; ++e)
                    im[kt][e] = (Bv[pt][e] > im[kt][e]) ? Bv[pt][e] : im[kt][e];
#pragma unroll
            for (int pt = 0; pt < 4; ++pt)
#pragma unroll
                for (int t = 0; t < 4; ++t)
                    acc[pt][t] = __builtin_amdgcn_mfma_f32_16x16x32_f16(A[t], Bv[pt], acc[pt][t], 0, 0, 0);
        }
#pragma unroll
        for (int pt = 0; pt < 4; ++pt)
#pragma unroll
            for (int t = 0; t < 4; ++t)
#pragma unroll
                for (int j = 0; j < 4; ++j) {
                    float v = acc[pt][t][j];
                    rmax[t][j] = fmaxf(rmax[t][j], v);
                    rmin[t][j] = fminf(rmin[t][j], v);
                    rsum[t][j] += v;
                    rsq[t][j]  += v * v;
                }
        __syncthreads();
        cur ^= 1;
    }

    if (wid == 0) {
#pragma unroll
        for (int kt = 0; kt < 4; ++kt)
            *(f16x8*)(cat + (size_t)(r0 + lr) * 512 + 128 + kt * 32 + lg * 8) = im[kt];
    }
#pragma unroll
    for (int t = 0; t < 4; ++t) {
        f16x4 vx, vn;
#pragma unroll
        for (int j = 0; j < 4; ++j) { vx[j] = (f16)rmax[t][j]; vn[j] = (f16)rmin[t][j]; }
        size_t base = (size_t)(r0 + lr) * 256 + ob + 16 * t + 4 * lg;
        *(f16x4*)(mx4 + base) = vx;
        *(f16x4*)(mn4 + base) = vn;
    }
    float* rep = strep + ((blockIdx.x & (NREP - 1)) << 10);
#pragma unroll
    for (int t = 0; t < 4; ++t)
#pragma unroll
        for (int j = 0; j < 4; ++j) {
            float s = rsum[t][j], q = rsq[t][j];
#pragma unroll
            for (int m2 = 1; m2 < 16; m2 <<= 1) { s += __shfl_xor(s, m2); q += __shfl_xor(q, m2); }
            if (lr == 0) {
                atomicAdd(rep + ob + 16 * t + 4 * lg + j, s);
                atomicAdd(rep + 512 + ob + 16 * t + 4 * lg + j, q);
            }
        }
}

// ---------- conv4 epilogue: BN+ReLU on max/min (monotone commute) -> cat[256:512) ----------
__global__ __launch_bounds__(256) void cat4_kernel(const f16* __restrict__ mx4,
                                                   const f16* __restrict__ mn4,
                                                   const float* __restrict__ scsh,
                                                   f16* __restrict__ cat) {
    int i = blockIdx.x * 256 + threadIdx.x;
    int r = i >> 8, ch = i & 255;
    float sc = scsh[ch], sh = scsh[512 + ch];
    float v  = (sc > 0.f) ? (float)mx4[i] : (float)mn4[i];
    cat[(size_t)r * 512 + 256 + ch] = (f16)fmaxf(fmaf(v, sc, sh), 0.f);
}

// ---------- conv5: waves share px, differ in ob (replica-bank stats) ----------
__global__ __launch_bounds__(256) void conv5_mfma(const f16* __restrict__ cat,
                                                  const f16* __restrict__ W,
                                                  float* __restrict__ out,
                                                  float* __restrict__ strep) {
    const int tid = threadIdx.x;
    const int lane = tid & 63, wid = tid >> 6;
    const int lr = lane & 15, lg = lane >> 4;
    const int p0 = blockIdx.x * 64;
    const int ob = blockIdx.y * 256 + wid * 64;

    f32x4 acc[4][4];
#pragma unroll
    for (int pt = 0; pt < 4; ++pt)
#pragma unroll
        for (int t = 0; t < 4; ++t) acc[pt][t] = (f32x4){0.f, 0.f, 0.f, 0.f};

#pragma unroll
    for (int kt = 0; kt < 16; ++kt) {
        const int koff = kt * 32 + lg * 8;
        f16x8 A[4];
#pragma unroll
        for (int t = 0; t < 4; ++t)
            A[t] = *(const f16x8*)(W + (size_t)(ob + 16 * t + lr) * 512 + koff);
#pragma unroll
        for (int pt = 0; pt < 4; ++pt) {
            f16x8 B = *(const f16x8*)(cat + (size_t)(p0 + pt * 16 + lr) * 512 + koff);
#pragma unroll
            for (int t = 0; t < 4; ++t)
                acc[pt][t] = __builtin_amdgcn_mfma_f32_16x16x32_f16(A[t], B, acc[pt][t], 0, 0, 0);
        }
    }
#pragma unroll
    for (int pt = 0; pt < 4; ++pt) {
        int px = p0 + pt * 16 + lr;
        int b = px >> 11, n = px & 2047;
#pragma unroll
        for (int t = 0; t < 4; ++t) {
#pragma unroll
            for (int j = 0; j < 4; ++j) {
                int o = ob + 16 * t + 4 * lg + j;
                out[((size_t)(b * 512 + o)) * 2048 + n] = acc[pt][t][j];
            }
        }
    }
    __shared__ float lsum[4][64], lsq[4][64];
#pragma unroll
    for (int t = 0; t < 4; ++t)
#pragma unroll
        for (int j = 0; j < 4; ++j) {
            float s = acc[0][t][j] + acc[1][t][j] + acc[2][t][j] + acc[3][t][j];
            float q = acc[0][t][j] * acc[0][t][j] + acc[1][t][j] * acc[1][t][j]
                    + acc[2][t][j] * acc[2][t][j] + acc[3][t][j] * acc[3][t][j];
#pragma unroll
            for (int m2 = 1; m2 < 16; m2 <<= 1) { s += __shfl_xor(s, m2); q += __shfl_xor(q, m2); }
            if (lr == 0) { lsum[wid][16 * t + 4 * lg + j] = s; lsq[wid][16 * t + 4 * lg + j] = q; }
        }
    __syncthreads();
    float* rep = strep + ((blockIdx.x & (NREP - 1)) << 10);
    if (tid < 256) {
        int w = tid >> 6, c = tid & 63;
        atomicAdd(rep + blockIdx.y * 256 + tid, lsum[w][c]);
        atomicAdd(rep + 512 + blockIdx.y * 256 + tid, lsq[w][c]);
    }
}

// ---------- BN finalize: sums NREP replica banks, zeroes them, emits f32+f16 scale|shift ----------
__global__ void finalize_kernel(float* __restrict__ strep, const float* __restrict__ g,
                                const float* __restrict__ bb, float* __restrict__ scsh,
                                f16* __restrict__ scshH, int C, float invM) {
    int c = threadIdx.x;
    if (c < C) {
        float s = 0.f, q = 0.f;
#pragma unroll 4
        for (int rr = 0; rr < NREP; ++rr) {
            s += strep[rr * 1024 + c];
            q += strep[rr * 1024 + 512 + c];
        }
#pragma unroll 4
        for (int rr = 0; rr < NREP; ++rr) {
            strep[rr * 1024 + c] = 0.f;
            strep[rr * 1024 + 512 + c] = 0.f;
        }
        float mean = s * invM;
        float var  = q * invM - mean * mean;
        float istd = rsqrtf(var + EPS_BN);
        float sc   = g[c] * istd;
        float sh   = bb[c] - mean * sc;
        scsh[c]        = sc;
        scsh[512 + c]  = sh;
        scshH[c]       = (f16)sc;
        scshH[512 + c] = (f16)sh;
    }
}

// ---------- vectorized catmax (k-major): f16x8 coalesced, BN+max over k -> cat ----------
template<int C>
__global__ __launch_bounds__(256) void catmax_vec(const f16* __restrict__ y,
                                                  const float* __restrict__ scsh,
                                                  f16* __restrict__ cat, int coff) {
    constexpr int CB = C / 8;
    int i  = blockIdx.x * 256 + threadIdx.x;
    int r  = i / CB;
    int cc = (i - r * CB) * 8;
    float sc[8], sh[8];
#pragma unroll
    for (int e = 0; e < 8; ++e) { sc[e] = scsh[cc + e]; sh[e] = scsh[512 + cc + e]; }
    float mx[8];
#pragma unroll
    for (int e = 0; e < 8; ++e) mx[e] = -3.3e38f;
#pragma unroll
    for (int k = 0; k < KK; ++k) {
        f16x8 v = *(const f16x8*)(y + ((size_t)k * BNP + r) * C + cc);
#pragma unroll
        for (int e = 0; e < 8; ++e)
            mx[e] = fmaxf(mx[e], fmaf((float)v[e], sc[e], sh[e]));
    }
    f16x8 o;
#pragma unroll
    for (int e = 0; e < 8; ++e) o[e] = (f16)fmaxf(mx[e], 0.f);
    *(f16x8*)(cat + (size_t)r * 512 + coff + cc) = o;
}

// ---------- final normalize + ReLU on conv5 output in place ----------
__global__ __launch_bounds__(256) void norm5_kernel(float* __restrict__ out,
                                                    const float* __restrict__ scsh) {
    int o = blockIdx.y;
    int r = blockIdx.x * 256 + threadIdx.x;
    int b = r >> 11, n = r & 2047;
    float sc = scsh[o], sh = scsh[512 + o];
    size_t i = ((size_t)(b * 512 + o)) * 2048 + n;
    float v = fmaf(out[i], sc, sh);
    out[i] = v > 0.f ? v : 0.f;
}

extern "C" void kernel_launch(void* const* d_in, const int* in_sizes, int n_in,
                              void* d_out, int out_size, void* d_ws, size_t ws_size,
                              hipStream_t stream) {
    float* out = (float*)d_out;
    if (ws_size < WS_NEED) {
        marker_kernel<<<1, 64, 0, stream>>>(out, 1000.0f + (float)(ws_size >> 20));
        return;
    }

    const float* x  = (const float*)d_in[0];
    const float* W1 = (const float*)d_in[1];
    const float* g1 = (const float*)d_in[2];
    const float* b1 = (const float*)d_in[3];
    const float* W2 = (const float*)d_in[4];
    const float* g2 = (const float*)d_in[5];
    const float* b2 = (const float*)d_in[6];
    const float* W3 = (const float*)d_in[7];
    const float* g3 = (const float*)d_in[8];
    const float* b3 = (const float*)d_in[9];
    const float* W4 = (const float*)d_in[10];
    const float* g4 = (const float*)d_in[11];
    const float* b4 = (const float*)d_in[12];
    const float* W5 = (const float*)d_in[13];
    const float* g5 = (const float*)d_in[14];
    const float* b5 = (const float*)d_in[15];

    char*  ws    = (char*)d_ws;
    int*   idx   = (int*)(ws + OFF_IDX);
    float* wt1   = (float*)(ws + OFF_WT1);
    f16*   wh2   = (f16*)(ws + OFF_WH2);
    f16*   wh3   = (f16*)(ws + OFF_WH3);
    f16*   wh4   = (f16*)(ws + OFF_WH4);
    f16*   wh5   = (f16*)(ws + OFF_WH5);
    f16*   scshH = (f16*)(ws + OFF_ST);                          // [5][1024] f16
    float* scsh  = (float*)(ws + OFF_SS);
    f16*   cat   = (f16*)(ws + OFF_CAT);
    f16*   y1    = (f16*)(ws + OFF_Y1);
    f16*   y2    = (f16*)(ws + OFF_Y2);
    f16*   y3    = (f16*)(ws + OFF_Y3);
    f16*   mx4   = (f16*)(ws + OFF_Y2);                          // y2 dead at L4
    f16*   mn4   = (f16*)(ws + OFF_Y2 + (size_t)BNP * 256 * 2);
    float* strep = (float*)(ws + OFF_REP);                       // [NREP][1024]

    hipMemsetAsync(strep, 0, (size_t)NREP * 1024 * 4, stream);   // once; finalize self-clears

    prep_weights<<<1024, 256, 0, stream>>>(W1, W2, W3, W4, W5, wt1, wh2, wh3, wh4, wh5);
    knn_kernel<<<4096, 256, 0, stream>>>(x, idx);

    const float invM  = 1.0f / (float)PT;
    const float invM5 = 1.0f / (float)BNP;

    // L1: 6 -> 64 (raw y1, stats fused into replica banks)
    conv1_kernel<<<PT / 256, 256, 0, stream>>>(x, idx, wt1, y1, strep);
    finalize_kernel<<<1, 512, 0, stream>>>(strep, g1, b1, scsh + 0, scshH + 0, 64, invM);
    catmax_vec<64><<<BNP * 8 / 256, 256, 0, stream>>>(y1, scsh + 0, cat, 0);

    // L2: 64 -> 64 (f16 BN1 on load; stats fused)
    conv_mfma_kernel<64, 1><<<PT / 256, 256, 0, stream>>>(y1, wh2, scshH + 0, y2, strep);
    finalize_kernel<<<1, 512, 0, stream>>>(strep, g2, b2, scsh + 1024, scshH + 1024, 64, invM);
    catmax_vec<64><<<BNP * 8 / 256, 256, 0, stream>>>(y2, scsh + 1024, cat, 64);

    // L3: 64 -> 128 (f16 BN2 on load; OBW=2; clobbers dead y1; stats fused)
    conv_mfma_kernel<64, 2><<<PT / 128, 256, 0, stream>>>(y2, wh3, scshH + 1024, y3, strep);
    finalize_kernel<<<1, 512, 0, stream>>>(strep, g3, b3, scsh + 2048, scshH + 2048, 128, invM);

    // L4: 128 -> 256, async-LDS-staged, f16 BN3 on load; stats + raw max/min + input catmax
    conv4_fused_mfma<<<BNP / 16, 256, 0, stream>>>(y3, wh4, scshH + 2048, strep, mx4, mn4, cat);
    finalize_kernel<<<1, 512, 0, stream>>>(strep, g4, b4, scsh + 3072, scshH + 3072, 256, invM);
    cat4_kernel<<<BNP, 256, 0, stream>>>(mx4, mn4, scsh + 3072, cat);

    // L5: 512 -> 512 on cat -> d_out raw (stats fused)
    conv5_mfma<<<dim3(BNP / 64, 2), 256, 0, stream>>>(cat, wh5, out, strep);
    finalize_kernel<<<1, 512, 0, stream>>>(strep, g5, b5, scsh + 4096, scshH + 4096, 512, invM5);
    norm5_kernel<<<dim3(BNP / 256, 512), 256, 0, stream>>>(out, scsh + 4096);
}

// Round 16
// 380.802 us; speedup vs baseline: 1.7058x; 1.0552x over previous
//
#include <hip/hip_runtime.h>
#include <hip/hip_bf16.h>

typedef _Float16 f16;
typedef _Float16 f16x8 __attribute__((ext_vector_type(8)));
typedef _Float16 f16x4 __attribute__((ext_vector_type(4)));
typedef float    f32x4 __attribute__((ext_vector_type(4)));
typedef unsigned long long u64;

constexpr int NB  = 8;
constexpr int NPT = 2048;
constexpr int KK  = 20;
constexpr int PT  = NB * NPT * KK;   // 327680 pixels, layers 1-4
constexpr int BNP = NB * NPT;        // 16384 points (= 2^14)
constexpr float EPS_BN = 1e-5f;
constexpr int NREP = 64;             // stats replica banks

// ---------- workspace layout (bytes) ----------
constexpr size_t OFF_IDX = 0;                                    // int [KK][BNP] (transposed)
constexpr size_t OFF_WT1 = OFF_IDX + (size_t)BNP * KK * 4;
constexpr size_t OFF_WH2 = OFF_WT1 + 384 * 4;
constexpr size_t OFF_WH3 = OFF_WH2 + 4096 * 2;
constexpr size_t OFF_WH4 = OFF_WH3 + 8192 * 2;
constexpr size_t OFF_WH5 = OFF_WH4 + 32768 * 2;
constexpr size_t OFF_ST  = OFF_WH5 + 262144 * 2;                 // scshH f16 [5][1024]
constexpr size_t OFF_SS  = OFF_ST + 5 * 1024 * 4;
constexpr size_t OFF_CAT = OFF_SS + 5 * 1024 * 4;                // f16 [BNP][512]
constexpr size_t OFF_Y3  = OFF_CAT + (size_t)BNP * 512 * 2;      // f16 [PT][128] (k-major pixels)
constexpr size_t OFF_Y1  = OFF_Y3 + (size_t)PT * 64 * 2;         // aliases upper half of y3
constexpr size_t OFF_Y2  = OFF_Y3 + (size_t)PT * 128 * 2;        // f16; L4: mx4|mn4; L5: y5
constexpr size_t OFF_REP = OFF_Y2 + (size_t)PT * 64 * 2;         // f32 [NREP][1024] = 256 KB
constexpr size_t WS_NEED = OFF_REP + (size_t)NREP * 1024 * 4;    // 144,836,096 B

// ---------- diagnostic ----------
__global__ void marker_kernel(float* __restrict__ out, float v) {
    if (threadIdx.x == 0 && blockIdx.x == 0) out[0] = v;
}

// ---------- async global->LDS (wave-uniform LDS base + lane*16B dest) ----------
__device__ __forceinline__ void gload16(const f16* g, f16* ldsbase) {
    __builtin_amdgcn_global_load_lds(
        (const __attribute__((address_space(1))) void*)g,
        (__attribute__((address_space(3))) void*)ldsbase, 16, 0, 0);
}

// ---------- weight prep ----------
__global__ __launch_bounds__(256) void prep_weights(
        const float* __restrict__ W1, const float* __restrict__ W2,
        const float* __restrict__ W3, const float* __restrict__ W4,
        const float* __restrict__ W5,
        float* __restrict__ wt1, f16* __restrict__ wh2, f16* __restrict__ wh3,
        f16* __restrict__ wh4, f16* __restrict__ wh5) {
    int i = blockIdx.x * 256 + threadIdx.x;
    if (i < 384)    { int o = i / 6, c = i - o * 6; wt1[c * 64 + o] = W1[i]; }
    if (i < 4096)   wh2[i] = (f16)W2[i];
    if (i < 8192)   wh3[i] = (f16)W3[i];
    if (i < 32768)  wh4[i] = (f16)W4[i];
    if (i < 262144) wh5[i] = (f16)W5[i];
}

// ---------- kNN v7: early-exit bisection + bitonic f64 refine ----------
__device__ __forceinline__ u64 mkkey(float d, int m) {
    unsigned u = __float_as_uint(d);
    u = (u & 0x80000000u) ? ~u : (u | 0x80000000u);
    return ((u64)u << 32) | (unsigned)(2047 - m);
}
__device__ __forceinline__ int key2m(u64 k) { return 2047 - (int)(k & 0xFFFFFFFFull); }

__device__ __forceinline__ void qins(u64 k, u64& q0, u64& q1, u64& q2, u64& q3, u64& spill) {
    bool c0 = k > q0, c1 = k > q1, c2 = k > q2, c3 = k > q3;
    u64 drop = c3 ? q3 : k;
    spill = spill > drop ? spill : drop;
    q3 = c2 ? q2 : (c3 ? k : q3);
    q2 = c1 ? q1 : (c2 ? k : q2);
    q1 = c0 ? q0 : (c1 ? k : q1);
    q0 = c0 ? k  : q0;
}

__global__ __launch_bounds__(256) void knn_kernel(const float* __restrict__ x,
                                                  int* __restrict__ idxo) {
    const int tid  = threadIdx.x;
    const int lane = tid & 63;
    const int wid  = tid >> 6;
    const int r    = blockIdx.x * 4 + wid;
    const int b    = r >> 11;
    const int n    = r & 2047;
    const float* xb = x + b * (3 * NPT);

    __shared__ float sqs[NPT];
    __shared__ int   cand[4][32];
#pragma unroll
    for (int i = 0; i < NPT / 256; ++i) {
        int m = i * 256 + tid;
        float a0 = xb[m], a1 = xb[NPT + m], a2 = xb[2 * NPT + m];
        sqs[m] = __fadd_rn(__fadd_rn(__fmul_rn(a0, a0), __fmul_rn(a1, a1)),
                           __fmul_rn(a2, a2));
    }
    __syncthreads();

    const float xn0 = xb[n], xn1 = xb[NPT + n], xn2 = xb[2 * NPT + n];
    const float sqn = sqs[n];

    auto dist2 = [&](int m) -> float {
        float dot = __fmaf_rn(xn0, xb[m],
                    __fmaf_rn(xn1, xb[NPT + m],
                    __fmul_rn(xn2, xb[2 * NPT + m])));
        return __fsub_rn(__fsub_rn(__fmul_rn(2.f, dot), sqn), sqs[m]);
    };

    u64 qa0 = 0, qa1 = 0, qa2 = 0, qa3 = 0, sA = 0;
    u64 qb0 = 0, qb1 = 0, qb2 = 0, qb3 = 0, sB = 0;
#pragma unroll
    for (int i = 0; i < 16; ++i) {
        int ma = i * 64 + lane;
        int mb = 1024 + ma;
        float da = dist2(ma);
        float db = dist2(mb);
        qins(mkkey(da, ma), qa0, qa1, qa2, qa3, sA);
        qins(mkkey(db, mb), qb0, qb1, qb2, qb3, sB);
    }
    u64 spill = sA > sB ? sA : sB;
    qins(qb0, qa0, qa1, qa2, qa3, spill);
    qins(qb1, qa0, qa1, qa2, qa3, spill);
    qins(qb2, qa0, qa1, qa2, qa3, spill);
    qins(qb3, qa0, qa1, qa2, qa3, spill);
    u64 q0 = qa0, q1 = qa1, q2 = qa2, q3 = qa3;

    // bisection with early exit: need any T with 26 <= count(>=T) <= 32
    int C = 0;
    unsigned lo = 0u, hi = 0xFFFFFFFFu;
#pragma unroll 1
    for (int it = 0; it < 32 && lo < hi; ++it) {
        unsigned span = hi - lo;
        unsigned mid  = lo + (span >> 1) + (span & 1);
        u64 M = (u64)mid << 32;
        int cnt = __popcll(__ballot(q0 >= M)) + __popcll(__ballot(q1 >= M))
                + __popcll(__ballot(q2 >= M)) + __popcll(__ballot(q3 >= M));
        if (cnt >= 26) {
            lo = mid;
            if (cnt <= 32) break;                    // window hit: good enough
        } else hi = mid - 1;
    }
    const u64 T64 = (u64)lo << 32;

    u64 b0 = __ballot(q0 >= T64), b1 = __ballot(q1 >= T64);
    u64 b2 = __ballot(q2 >= T64), b3 = __ballot(q3 >= T64);
    int n0 = __popcll(b0), n1 = __popcll(b1), n2 = __popcll(b2), n3 = __popcll(b3);
    C = n0 + n1 + n2 + n3;
    bool conflict = (__ballot(spill >= T64) != 0ull) || (C > 32) || (C < 26);

    if (!conflict) {
        u64 ltm = (1ull << lane) - 1ull;
        if (q0 >= T64) cand[wid][__popcll(b0 & ltm)] = key2m(q0);
        if (q1 >= T64) cand[wid][n0 + __popcll(b1 & ltm)] = key2m(q1);
        if (q2 >= T64) cand[wid][n0 + n1 + __popcll(b2 & ltm)] = key2m(q2);
        if (q3 >= T64) cand[wid][n0 + n1 + n2 + __popcll(b3 & ltm)] = key2m(q3);
    } else {
        C = 26;
#pragma unroll 1
        for (int t = 0; t < 26; ++t) {
            u64 v = q0;
#pragma unroll
            for (int s = 1; s < 64; s <<= 1) {
                u64 ov = __shfl_xor(v, s);
                if (ov > v) v = ov;
            }
            if (lane == 0) cand[wid][t] = key2m(v);
            if (q0 == v) {
                q0 = q1; q1 = q2; q2 = q3; q3 = 0;
                if (!(q0 > spill)) {
                    q0 = q1 = q2 = q3 = 0; spill = 0;
                    for (int ii = 0; ii < 32; ++ii) {
                        int mr = ii * 64 + lane;
                        u64 kr = mkkey(dist2(mr), mr);
                        if (kr < v) qins(kr, q0, q1, q2, q3, spill);
                    }
                }
            }
        }
    }
    __syncthreads();

    // exact f64 refine; sort candidates by (dd desc, m asc) via 64-lane bitonic
    int mm = (lane < C) ? cand[wid][lane] : 0;
    const double dxn0 = (double)xn0, dxn1 = (double)xn1, dxn2 = (double)xn2;
    const double dsqn = dxn0 * dxn0 + dxn1 * dxn1 + dxn2 * dxn2;
    double xm0 = (double)xb[mm], xm1 = (double)xb[NPT + mm], xm2 = (double)xb[2 * NPT + mm];
    double ddot = dxn0 * xm0 + dxn1 * xm1 + dxn2 * xm2;
    double dsqm = xm0 * xm0 + xm1 * xm1 + xm2 * xm2;
    double dd   = 2.0 * ddot - dsqn - dsqm;

    u64 ku = 0; unsigned tb = 0;
    if (lane < C) {
        u64 du = (u64)__double_as_longlong(dd);
        ku = (du & 0x8000000000000000ull) ? ~du : (du | 0x8000000000000000ull);
        tb = (unsigned)(2047 - mm);
    }
#pragma unroll
    for (int k = 2; k <= 64; k <<= 1)
#pragma unroll
        for (int j = k >> 1; j > 0; j >>= 1) {
            u64      ok = __shfl_xor(ku, j);
            unsigned ot = __shfl_xor(tb, j);
            bool dirDesc = ((lane & k) == 0);
            bool lower   = ((lane & j) == 0);
            bool myGT    = (ku > ok) || (ku == ok && tb > ot);
            bool keep    = (myGT == (dirDesc == lower));
            if (!keep) { ku = ok; tb = ot; }
        }
    if (lane < KK) idxo[lane * BNP + r] = 2047 - (int)tb;
}

// ---------- conv1 (k-major pixels) + fused per-channel stats (replica banks) ----------
__global__ __launch_bounds__(256) void conv1_kernel(const float* __restrict__ x,
                                                    const int* __restrict__ idx,
                                                    const float* __restrict__ Wt,
                                                    f16* __restrict__ y,
                                                    float* __restrict__ strep) {
    const int tid = threadIdx.x, lane = tid & 63, wid = tid >> 6;
    int p = blockIdx.x * 256 + tid;
    int r = p & (BNP - 1);
    int n = r & 2047;
    int b = r >> 11;
    int m = idx[p];
    const float* xb = x + b * (3 * NPT);
    float f3 = xb[n], f4 = xb[NPT + n], f5 = xb[2 * NPT + n];
    float f0 = xb[m] - f3, f1 = xb[NPT + m] - f4, f2 = xb[2 * NPT + m] - f5;
    float fv[6] = { f0, f1, f2, f3, f4, f5 };

    float acc[64];
#pragma unroll
    for (int o = 0; o < 64; ++o) acc[o] = 0.f;
#pragma unroll
    for (int c = 0; c < 6; ++c) {
        float hv = fv[c];
#pragma unroll
        for (int o = 0; o < 64; ++o) acc[o] = fmaf(Wt[c * 64 + o], hv, acc[o]);
    }
    f16* yp = y + (size_t)p * 64;
#pragma unroll
    for (int o = 0; o < 64; ++o) yp[o] = (f16)acc[o];

    __shared__ float lsum[4][64], lsq[4][64];
#pragma unroll
    for (int o = 0; o < 64; ++o) {
        float s = acc[o], q = acc[o] * acc[o];
#pragma unroll
        for (int off = 32; off >= 1; off >>= 1) { s += __shfl_xor(s, off); q += __shfl_xor(q, off); }
        if (lane == 0) { lsum[wid][o] = s; lsq[wid][o] = q; }
    }
    __syncthreads();
    float* rep = strep + ((blockIdx.x & (NREP - 1)) << 10);
    if (tid < 64) {
        atomicAdd(rep + tid,       lsum[0][tid] + lsum[1][tid] + lsum[2][tid] + lsum[3][tid]);
        atomicAdd(rep + 512 + tid, lsq[0][tid] + lsq[1][tid] + lsq[2][tid] + lsq[3][tid]);
    }
}

// ---------- MFMA GEMM, f16 BN-on-load, fused stats (L2, L3; replica banks) ----------
template<int CIN, int OBW>
__global__ __launch_bounds__(256) void conv_mfma_kernel(const f16* __restrict__ h,
                                                        const f16* __restrict__ W,
                                                        const f16* __restrict__ scshH,
                                                        f16* __restrict__ y,
                                                        float* __restrict__ strep) {
    constexpr int COUT = OBW * 64;
    const int tid = threadIdx.x, lane = tid & 63, wid = tid >> 6;
    const int lr = lane & 15, lg = lane >> 4;
    const int p0 = blockIdx.x * (256 / OBW) + (wid / OBW) * 64;
    const int ob = (wid & (OBW - 1)) * 64;

    f16x8 Bn[CIN / 32][4];
#pragma unroll
    for (int kt = 0; kt < CIN / 32; ++kt) {
        const int koff = kt * 32 + lg * 8;
        f16x8 scf = *(const f16x8*)(scshH + koff);
        f16x8 shf = *(const f16x8*)(scshH + 512 + koff);
#pragma unroll
        for (int pt = 0; pt < 4; ++pt) {
            f16x8 raw = *(const f16x8*)(h + (size_t)(p0 + pt * 16 + lr) * CIN + koff);
            f16x8 t = raw * scf + shf;
            f16x8 Bv;
#pragma unroll
            for (int e = 0; e < 8; ++e)
                Bv[e] = t[e] > (f16)0.f ? t[e] : (f16)0.f;
            Bn[kt][pt] = Bv;
        }
    }

    f32x4 acc[4][4];
#pragma unroll
    for (int pt = 0; pt < 4; ++pt)
#pragma unroll
        for (int t = 0; t < 4; ++t) acc[pt][t] = (f32x4){0.f, 0.f, 0.f, 0.f};

#pragma unroll
    for (int kt = 0; kt < CIN / 32; ++kt) {
        const int koff = kt * 32 + lg * 8;
        f16x8 A[4];
#pragma unroll
        for (int t = 0; t < 4; ++t)
            A[t] = *(const f16x8*)(W + (size_t)(ob + 16 * t + lr) * CIN + koff);
#pragma unroll
        for (int pt = 0; pt < 4; ++pt)
#pragma unroll
            for (int t = 0; t < 4; ++t)
                acc[pt][t] = __builtin_amdgcn_mfma_f32_16x16x32_f16(A[t], Bn[kt][pt], acc[pt][t], 0, 0, 0);
    }
#pragma unroll
    for (int pt = 0; pt < 4; ++pt) {
        int px = p0 + pt * 16 + lr;
#pragma unroll
        for (int t = 0; t < 4; ++t) {
            f16x4 v;
            v[0] = (f16)acc[pt][t][0]; v[1] = (f16)acc[pt][t][1];
            v[2] = (f16)acc[pt][t][2]; v[3] = (f16)acc[pt][t][3];
            *(f16x4*)(y + (size_t)px * COUT + ob + 16 * t + 4 * lg) = v;
        }
    }
    __shared__ float lsum[4][64], lsq[4][64];
#pragma unroll
    for (int t = 0; t < 4; ++t)
#pragma unroll
        for (int j = 0; j < 4; ++j) {
            float s = acc[0][t][j] + acc[1][t][j] + acc[2][t][j] + acc[3][t][j];
            float q = acc[0][t][j] * acc[0][t][j] + acc[1][t][j] * acc[1][t][j]
                    + acc[2][t][j] * acc[2][t][j] + acc[3][t][j] * acc[3][t][j];
#pragma unroll
            for (int m2 = 1; m2 < 16; m2 <<= 1) { s += __shfl_xor(s, m2); q += __shfl_xor(q, m2); }
            if (lr == 0) { lsum[wid][16 * t + 4 * lg + j] = s; lsq[wid][16 * t + 4 * lg + j] = q; }
        }
    __syncthreads();
    float* rep = strep + ((blockIdx.x & (NREP - 1)) << 10);
    if (tid < COUT) {
        int obIdx = tid >> 6, c = tid & 63;
        float S = 0.f, Q = 0.f;
#pragma unroll
        for (int w = obIdx; w < 4; w += OBW) { S += lsum[w][c]; Q += lsq[w][c]; }
        atomicAdd(rep + tid, S);
        atomicAdd(rep + 512 + tid, Q);
    }
}

// ---------- conv4: async LDS-staged y3, f16 BN-on-load, register reductions ----------
__global__ __launch_bounds__(256) void conv4_fused_mfma(const f16* __restrict__ h,
                                                        const f16* __restrict__ W,
                                                        const f16* __restrict__ scshH,
                                                        float* __restrict__ strep,
                                                        f16* __restrict__ mx4,
                                                        f16* __restrict__ mn4,
                                                        f16* __restrict__ cat) {
    const int tid = threadIdx.x, lane = tid & 63, wid = tid >> 6;
    const int lr = lane & 15, lg = lane >> 4;
    const int r0 = blockIdx.x * 16;
    const int ob = wid * 64;

    __shared__ f16 sb[2][4][16][128];

    f32x4 rmax[4], rmin[4], rsum[4], rsq[4];
#pragma unroll
    for (int t = 0; t < 4; ++t) {
        rmax[t] = (f32x4){-3.3e38f, -3.3e38f, -3.3e38f, -3.3e38f};
        rmin[t] = (f32x4){ 3.3e38f,  3.3e38f,  3.3e38f,  3.3e38f};
        rsum[t] = (f32x4){0.f, 0.f, 0.f, 0.f};
        rsq[t]  = (f32x4){0.f, 0.f, 0.f, 0.f};
    }
    f16x8 im[4];
#pragma unroll
    for (int kt = 0; kt < 4; ++kt)
#pragma unroll
        for (int e = 0; e < 8; ++e) im[kt][e] = (f16)0.f;

    auto STAGE = [&](int buf, int kc) {
        const f16* gk = h + ((size_t)(kc * 4 + wid) * BNP + r0) * 128;
#pragma unroll
        for (int i = 0; i < 4; ++i) {
            int rr = i * 4 + (lane >> 4);
            int cc = (lane & 15) ^ rr;
            gload16(gk + (size_t)rr * 128 + cc * 8, &sb[buf][wid][i * 4][0]);
        }
    };

    STAGE(0, 0);
    __syncthreads();

    int cur = 0;
#pragma unroll 1
    for (int kc = 0; kc < 5; ++kc) {
        if (kc < 4) STAGE(cur ^ 1, kc + 1);

        f32x4 acc[4][4];
#pragma unroll
        for (int pt = 0; pt < 4; ++pt)
#pragma unroll
            for (int t = 0; t < 4; ++t) acc[pt][t] = (f32x4){0.f, 0.f, 0.f, 0.f};

#pragma unroll
        for (int kt = 0; kt < 4; ++kt) {
            const int koff = kt * 32 + lg * 8;
            f16x8 scf = *(const f16x8*)(scshH + koff);
            f16x8 shf = *(const f16x8*)(scshH + 512 + koff);
            f16x8 A[4];
#pragma unroll
            for (int t = 0; t < 4; ++t)
                A[t] = *(const f16x8*)(W + (size_t)(ob + 16 * t + lr) * 128 + koff);
            f16x8 Bv[4];
#pragma unroll
            for (int pt = 0; pt < 4; ++pt) {
                int cpos = (kt * 4 + lg) ^ lr;
                f16x8 raw = *(const f16x8*)(&sb[cur][pt][lr][cpos * 8]);
                f16x8 t = raw * scf + shf;
                f16x8 Bn;
#pragma unroll
                for (int e = 0; e < 8; ++e)
                    Bn[e] = t[e] > (f16)0.f ? t[e] : (f16)0.f;
                Bv[pt] = Bn;
            }
#pragma unroll
            for (int pt = 0; pt < 4; ++pt)
#pragma unroll
                for (int e = 0; e < 8; ++e)
                    im[kt][e] = (Bv[pt][e] > im[kt][e]) ? Bv[pt][e] : im[kt][e];
#pragma unroll
            for (int pt = 0; pt < 4; ++pt)
#pragma unroll
                for (int t = 0; t < 4; ++t)
                    acc[pt][t] = __builtin_amdgcn_mfma_f32_16x16x32_f16(A[t], Bv[pt], acc[pt][t], 0, 0, 0);
        }
#pragma unroll
        for (int pt = 0; pt < 4; ++pt)
#pragma unroll
            for (int t = 0; t < 4; ++t)
#pragma unroll
                for (int j = 0; j < 4; ++j) {
                    float v = acc[pt][t][j];
                    rmax[t][j] = fmaxf(rmax[t][j], v);
                    rmin[t][j] = fminf(rmin[t][j], v);
                    rsum[t][j] += v;
                    rsq[t][j]  += v * v;
                }
        __syncthreads();
        cur ^= 1;
    }

    if (wid == 0) {
#pragma unroll
        for (int kt = 0; kt < 4; ++kt)
            *(f16x8*)(cat + (size_t)(r0 + lr) * 512 + 128 + kt * 32 + lg * 8) = im[kt];
    }
#pragma unroll
    for (int t = 0; t < 4; ++t) {
        f16x4 vx, vn;
#pragma unroll
        for (int j = 0; j < 4; ++j) { vx[j] = (f16)rmax[t][j]; vn[j] = (f16)rmin[t][j]; }
        size_t base = (size_t)(r0 + lr) * 256 + ob + 16 * t + 4 * lg;
        *(f16x4*)(mx4 + base) = vx;
        *(f16x4*)(mn4 + base) = vn;
    }
    float* rep = strep + ((blockIdx.x & (NREP - 1)) << 10);
#pragma unroll
    for (int t = 0; t < 4; ++t)
#pragma unroll
        for (int j = 0; j < 4; ++j) {
            float s = rsum[t][j], q = rsq[t][j];
#pragma unroll
            for (int m2 = 1; m2 < 16; m2 <<= 1) { s += __shfl_xor(s, m2); q += __shfl_xor(q, m2); }
            if (lr == 0) {
                atomicAdd(rep + ob + 16 * t + 4 * lg + j, s);
                atomicAdd(rep + 512 + ob + 16 * t + 4 * lg + j, q);
            }
        }
}

// ---------- conv4 epilogue: BN+ReLU on max/min (monotone commute) -> cat[256:512) ----------
__global__ __launch_bounds__(256) void cat4_kernel(const f16* __restrict__ mx4,
                                                   const f16* __restrict__ mn4,
                                                   const float* __restrict__ scsh,
                                                   f16* __restrict__ cat) {
    int i = blockIdx.x * 256 + threadIdx.x;
    int r = i >> 8, ch = i & 255;
    float sc = scsh[ch], sh = scsh[512 + ch];
    float v  = (sc > 0.f) ? (float)mx4[i] : (float)mn4[i];
    cat[(size_t)r * 512 + 256 + ch] = (f16)fmaxf(fmaf(v, sc, sh), 0.f);
}

// ---------- conv5: waves share px, differ in ob; writes raw y5 f16 (o-major) ----------
__global__ __launch_bounds__(256) void conv5_mfma(const f16* __restrict__ cat,
                                                  const f16* __restrict__ W,
                                                  f16* __restrict__ y5,
                                                  float* __restrict__ strep) {
    const int tid = threadIdx.x;
    const int lane = tid & 63, wid = tid >> 6;
    const int lr = lane & 15, lg = lane >> 4;
    const int p0 = blockIdx.x * 64;
    const int ob = blockIdx.y * 256 + wid * 64;

    f32x4 acc[4][4];
#pragma unroll
    for (int pt = 0; pt < 4; ++pt)
#pragma unroll
        for (int t = 0; t < 4; ++t) acc[pt][t] = (f32x4){0.f, 0.f, 0.f, 0.f};

#pragma unroll
    for (int kt = 0; kt < 16; ++kt) {
        const int koff = kt * 32 + lg * 8;
        f16x8 A[4];
#pragma unroll
        for (int t = 0; t < 4; ++t)
            A[t] = *(const f16x8*)(W + (size_t)(ob + 16 * t + lr) * 512 + koff);
#pragma unroll
        for (int pt = 0; pt < 4; ++pt) {
            f16x8 B = *(const f16x8*)(cat + (size_t)(p0 + pt * 16 + lr) * 512 + koff);
#pragma unroll
            for (int t = 0; t < 4; ++t)
                acc[pt][t] = __builtin_amdgcn_mfma_f32_16x16x32_f16(A[t], B, acc[pt][t], 0, 0, 0);
        }
    }
#pragma unroll
    for (int pt = 0; pt < 4; ++pt) {
        int px = p0 + pt * 16 + lr;
#pragma unroll
        for (int t = 0; t < 4; ++t)
#pragma unroll
            for (int j = 0; j < 4; ++j) {
                int o = ob + 16 * t + 4 * lg + j;
                y5[(size_t)o * BNP + px] = (f16)acc[pt][t][j];   // coalesced along px
            }
    }
    __shared__ float lsum[4][64], lsq[4][64];
#pragma unroll
    for (int t = 0; t < 4; ++t)
#pragma unroll
        for (int j = 0; j < 4; ++j) {
            float s = acc[0][t][j] + acc[1][t][j] + acc[2][t][j] + acc[3][t][j];
            float q = acc[0][t][j] * acc[0][t][j] + acc[1][t][j] * acc[1][t][j]
                    + acc[2][t][j] * acc[2][t][j] + acc[3][t][j] * acc[3][t][j];
#pragma unroll
            for (int m2 = 1; m2 < 16; m2 <<= 1) { s += __shfl_xor(s, m2); q += __shfl_xor(q, m2); }
            if (lr == 0) { lsum[wid][16 * t + 4 * lg + j] = s; lsq[wid][16 * t + 4 * lg + j] = q; }
        }
    __syncthreads();
    float* rep = strep + ((blockIdx.x & (NREP - 1)) << 10);
    if (tid < 256) {
        int w = tid >> 6, c = tid & 63;
        atomicAdd(rep + blockIdx.y * 256 + tid, lsum[w][c]);
        atomicAdd(rep + 512 + blockIdx.y * 256 + tid, lsq[w][c]);
    }
}

// ---------- BN finalize: sums NREP replica banks, zeroes them, emits f32+f16 scale|shift ----------
__global__ void finalize_kernel(float* __restrict__ strep, const float* __restrict__ g,
                                const float* __restrict__ bb, float* __restrict__ scsh,
                                f16* __restrict__ scshH, int C, float invM) {
    int c = threadIdx.x;
    if (c < C) {
        float s = 0.f, q = 0.f;
#pragma unroll 4
        for (int rr = 0; rr < NREP; ++rr) {
            s += strep[rr * 1024 + c];
            q += strep[rr * 1024 + 512 + c];
        }
#pragma unroll 4
        for (int rr = 0; rr < NREP; ++rr) {
            strep[rr * 1024 + c] = 0.f;
            strep[rr * 1024 + 512 + c] = 0.f;
        }
        float mean = s * invM;
        float var  = q * invM - mean * mean;
        float istd = rsqrtf(var + EPS_BN);
        float sc   = g[c] * istd;
        float sh   = bb[c] - mean * sc;
        scsh[c]        = sc;
        scsh[512 + c]  = sh;
        scshH[c]       = (f16)sc;
        scshH[512 + c] = (f16)sh;
    }
}

// ---------- vectorized catmax (k-major): f16x8 coalesced, BN+max over k -> cat ----------
template<int C>
__global__ __launch_bounds__(256) void catmax_vec(const f16* __restrict__ y,
                                                  const float* __restrict__ scsh,
                                                  f16* __restrict__ cat, int coff) {
    constexpr int CB = C / 8;
    int i  = blockIdx.x * 256 + threadIdx.x;
    int r  = i / CB;
    int cc = (i - r * CB) * 8;
    float sc[8], sh[8];
#pragma unroll
    for (int e = 0; e < 8; ++e) { sc[e] = scsh[cc + e]; sh[e] = scsh[512 + cc + e]; }
    float mx[8];
#pragma unroll
    for (int e = 0; e < 8; ++e) mx[e] = -3.3e38f;
#pragma unroll
    for (int k = 0; k < KK; ++k) {
        f16x8 v = *(const f16x8*)(y + ((size_t)k * BNP + r) * C + cc);
#pragma unroll
        for (int e = 0; e < 8; ++e)
            mx[e] = fmaxf(mx[e], fmaf((float)v[e], sc[e], sh[e]));
    }
    f16x8 o;
#pragma unroll
    for (int e = 0; e < 8; ++e) o[e] = (f16)fmaxf(mx[e], 0.f);
    *(f16x8*)(cat + (size_t)r * 512 + coff + cc) = o;
}

// ---------- norm5 v2: read y5 f16 (o-major), BN+ReLU, write out f32 [b][512][n] ----------
__global__ __launch_bounds__(256) void norm5_kernel(const f16* __restrict__ y5,
                                                    const float* __restrict__ scsh,
                                                    float* __restrict__ out) {
    int i  = blockIdx.x * 256 + threadIdx.x;        // BNP*512/4 elements
    int o  = i >> 12;
    int p4 = (i & 4095) * 4;
    float sc = scsh[o], sh = scsh[512 + o];
    f16x4 v = *(const f16x4*)(y5 + (size_t)o * BNP + p4);
    int b = p4 >> 11, n = p4 & 2047;
    float4 w;
    w.x = fmaxf(fmaf((float)v[0], sc, sh), 0.f);
    w.y = fmaxf(fmaf((float)v[1], sc, sh), 0.f);
    w.z = fmaxf(fmaf((float)v[2], sc, sh), 0.f);
    w.w = fmaxf(fmaf((float)v[3], sc, sh), 0.f);
    *(float4*)(out + ((size_t)(b * 512 + o)) * 2048 + n) = w;
}

extern "C" void kernel_launch(void* const* d_in, const int* in_sizes, int n_in,
                              void* d_out, int out_size, void* d_ws, size_t ws_size,
                              hipStream_t stream) {
    float* out = (float*)d_out;
    if (ws_size < WS_NEED) {
        marker_kernel<<<1, 64, 0, stream>>>(out, 1000.0f + (float)(ws_size >> 20));
        return;
    }

    const float* x  = (const float*)d_in[0];
    const float* W1 = (const float*)d_in[1];
    const float* g1 = (const float*)d_in[2];
    const float* b1 = (const float*)d_in[3];
    const float* W2 = (const float*)d_in[4];
    const float* g2 = (const float*)d_in[5];
    const float* b2 = (const float*)d_in[6];
    const float* W3 = (const float*)d_in[7];
    const float* g3 = (const float*)d_in[8];
    const float* b3 = (const float*)d_in[9];
    const float* W4 = (const float*)d_in[10];
    const float* g4 = (const float*)d_in[11];
    const float* b4 = (const float*)d_in[12];
    const float* W5 = (const float*)d_in[13];
    const float* g5 = (const float*)d_in[14];
    const float* b5 = (const float*)d_in[15];

    char*  ws    = (char*)d_ws;
    int*   idx   = (int*)(ws + OFF_IDX);
    float* wt1   = (float*)(ws + OFF_WT1);
    f16*   wh2   = (f16*)(ws + OFF_WH2);
    f16*   wh3   = (f16*)(ws + OFF_WH3);
    f16*   wh4   = (f16*)(ws + OFF_WH4);
    f16*   wh5   = (f16*)(ws + OFF_WH5);
    f16*   scshH = (f16*)(ws + OFF_ST);
    float* scsh  = (float*)(ws + OFF_SS);
    f16*   cat   = (f16*)(ws + OFF_CAT);
    f16*   y1    = (f16*)(ws + OFF_Y1);
    f16*   y2    = (f16*)(ws + OFF_Y2);
    f16*   y3    = (f16*)(ws + OFF_Y3);
    f16*   mx4   = (f16*)(ws + OFF_Y2);                          // y2 dead at L4
    f16*   mn4   = (f16*)(ws + OFF_Y2 + (size_t)BNP * 256 * 2);
    f16*   y5    = (f16*)(ws + OFF_Y2);                          // mx4/mn4 dead after cat4
    float* strep = (float*)(ws + OFF_REP);

    hipMemsetAsync(strep, 0, (size_t)NREP * 1024 * 4, stream);

    prep_weights<<<1024, 256, 0, stream>>>(W1, W2, W3, W4, W5, wt1, wh2, wh3, wh4, wh5);
    knn_kernel<<<4096, 256, 0, stream>>>(x, idx);

    const float invM  = 1.0f / (float)PT;
    const float invM5 = 1.0f / (float)BNP;

    // L1
    conv1_kernel<<<PT / 256, 256, 0, stream>>>(x, idx, wt1, y1, strep);
    finalize_kernel<<<1, 512, 0, stream>>>(strep, g1, b1, scsh + 0, scshH + 0, 64, invM);
    catmax_vec<64><<<BNP * 8 / 256, 256, 0, stream>>>(y1, scsh + 0, cat, 0);

    // L2
    conv_mfma_kernel<64, 1><<<PT / 256, 256, 0, stream>>>(y1, wh2, scshH + 0, y2, strep);
    finalize_kernel<<<1, 512, 0, stream>>>(strep, g2, b2, scsh + 1024, scshH + 1024, 64, invM);
    catmax_vec<64><<<BNP * 8 / 256, 256, 0, stream>>>(y2, scsh + 1024, cat, 64);

    // L3
    conv_mfma_kernel<64, 2><<<PT / 128, 256, 0, stream>>>(y2, wh3, scshH + 1024, y3, strep);
    finalize_kernel<<<1, 512, 0, stream>>>(strep, g3, b3, scsh + 2048, scshH + 2048, 128, invM);

    // L4
    conv4_fused_mfma<<<BNP / 16, 256, 0, stream>>>(y3, wh4, scshH + 2048, strep, mx4, mn4, cat);
    finalize_kernel<<<1, 512, 0, stream>>>(strep, g4, b4, scsh + 3072, scshH + 3072, 256, invM);
    cat4_kernel<<<BNP, 256, 0, stream>>>(mx4, mn4, scsh + 3072, cat);

    // L5: conv5 -> y5 f16; finalize; norm5 -> d_out
    conv5_mfma<<<dim3(BNP / 64, 2), 256, 0, stream>>>(cat, wh5, y5, strep);
    finalize_kernel<<<1, 512, 0, stream>>>(strep, g5, b5, scsh + 4096, scshH + 4096, 512, invM5);
    norm5_kernel<<<BNP * 512 / 4 / 256, 256, 0, stream>>>(y5, scsh + 4096, out);
}